// Round 1
// baseline (900.068 us; speedup 1.0000x reference)
//
#include <hip/hip_runtime.h>
#include <hip/hip_bf16.h>
#include <stdint.h>

typedef unsigned short ushort_t;
typedef unsigned int uint_t;

typedef __bf16 bf16x8 __attribute__((ext_vector_type(8)));
typedef float f32x4 __attribute__((ext_vector_type(4)));
typedef short short4v __attribute__((ext_vector_type(4)));

typedef const __attribute__((address_space(1))) void gv_t;
typedef __attribute__((address_space(3))) void lv_t;

__device__ __forceinline__ ushort_t f2b(float f) {
  uint_t u = __builtin_bit_cast(uint_t, f);
  u += 0x7FFFu + ((u >> 16) & 1u);   // round-to-nearest-even
  return (ushort_t)(u >> 16);
}
__device__ __forceinline__ float b2f(ushort_t s) {
  return __builtin_bit_cast(float, (uint_t)s << 16);
}
constexpr int ilog2c(int x) { return x <= 1 ? 0 : 1 + ilog2c(x >> 1); }

constexpr int Tt = 16, Cc = 256, Hh = 64, Ww = 64, DKc = 128;

// ---------------- tokenize Q/K: (B*T,128,H,W) slice -> (b, n, d) bf16 row-major ----------------
template<int PH, int PW, int CBASE, int NP>
__global__ __launch_bounds__(256) void tok_qk(const float* __restrict__ src, ushort_t* __restrict__ dst) {
  constexpr int OHN = Hh / PH, OWN = Ww / PW, DP = DKc * PH * PW, OHW = OHN * OWN;
  const int id = blockIdx.x * 256 + threadIdx.x;
  const int py = id & (PH - 1);
  const int c  = (id >> ilog2c(PH)) & (DKc - 1);
  const int n  = (id >> (ilog2c(PH) + 7)) & (NP - 1);
  const int b  = id >> (ilog2c(PH) + 7 + ilog2c(NP));
  const int t  = n >> ilog2c(OHW);
  const int rem = n & (OHW - 1);
  const int oh = rem >> ilog2c(OWN);
  const int ow = rem & (OWN - 1);
  const float* s = src + (((size_t)((b * Tt + t) * Cc + CBASE + c)) << 12)
                       + ((oh * PH + py) << 6) + ow * PW;
  ushort_t* d = dst + (size_t)(b * NP + n) * DP + (c * PH + py) * PW;
  float4 f0 = *(const float4*)s;
  short4v o0; o0[0] = f2b(f0.x); o0[1] = f2b(f0.y); o0[2] = f2b(f0.z); o0[3] = f2b(f0.w);
  *(short4v*)d = o0;
  if constexpr (PW == 8) {
    float4 f1 = *(const float4*)(s + 4);
    short4v o1; o1[0] = f2b(f1.x); o1[1] = f2b(f1.y); o1[2] = f2b(f1.z); o1[3] = f2b(f1.w);
    *(short4v*)(d + 4) = o1;
  }
}

// ---------------- tokenize V transposed: -> (b, d, n) bf16 row-major ----------------
template<int PH, int PW, int CBASE, int NP>
__global__ __launch_bounds__(256) void tok_vt(const float* __restrict__ src, ushort_t* __restrict__ dst) {
  constexpr int OHN = Hh / PH, OWN = Ww / PW, DP = DKc * PH * PW;
  constexpr int CH = PW, NCH = OWN / CH;
  const int id  = blockIdx.x * 256 + threadIdx.x;
  const int owc = id & (NCH - 1);
  const int oh  = (id >> ilog2c(NCH)) & (OHN - 1);
  const int t   = (id >> (ilog2c(NCH) + ilog2c(OHN))) & (Tt - 1);
  const int dd  = (id >> (ilog2c(NCH) + ilog2c(OHN) + 4)) & (DP - 1);
  const int b   = id >> (ilog2c(NCH) + ilog2c(OHN) + 4 + ilog2c(DP));
  const int c   = dd >> ilog2c(PH * PW);
  const int py  = (dd >> ilog2c(PW)) & (PH - 1);
  const int px  = dd & (PW - 1);
  const float* s = src + (((size_t)((b * Tt + t) * Cc + CBASE + c)) << 12)
                       + ((oh * PH + py) << 6) + px;
  const int n0 = (t * OHN + oh) * OWN + owc * CH;
  ushort_t* d = dst + (size_t)(b * DP + dd) * NP + n0;
  short4v o;
  #pragma unroll
  for (int j = 0; j < 4; ++j) o[j] = f2b(s[(owc * CH + j) * PW]);
  *(short4v*)d = o;
  if constexpr (CH == 8) {
    short4v o2;
    #pragma unroll
    for (int j = 0; j < 4; ++j) o2[j] = f2b(s[(owc * CH + 4 + j) * PW]);
    *(short4v*)(d + 4) = o2;
  }
}

// ---------------- NT GEMM: C(MxN) = A(MxK) * B(NxK)^T, bf16 in, 128x128 tile ----------------
// EPI 0: write bf16 scores*scale to P (row-major, ld = NP)
// EPI 1: scatter fp32 into d_out via from_tokens mapping
template<int EPI, int KITERS, int LDK, int NP, int PH, int PW, int CBASE>
__global__ __launch_bounds__(256) void gemm_nt(const ushort_t* __restrict__ A, const ushort_t* __restrict__ B,
                                               size_t aBatch, size_t bBatch,
                                               void* __restrict__ outPtr, size_t oBatch, float scale) {
  __shared__ ushort_t As[128 * 32];
  __shared__ ushort_t Bs[128 * 32];
  const int tid = threadIdx.x;
  const int w = tid >> 6, l = tid & 63;
  const int bz = blockIdx.z;
  const int rowBase = blockIdx.y * 128, colBase = blockIdx.x * 128;
  const ushort_t* Ab = A + (size_t)bz * aBatch;
  const ushort_t* Bb = B + (size_t)bz * bBatch;
  f32x4 acc[4][4] = {};
  const int wr = w >> 1, wc = w & 1;
  const int lr = l & 15, lk = l >> 4;
  const int srow = l >> 2, sslot = l & 3;

  for (int kt = 0; kt < KITERS; ++kt) {
    const int k0 = kt * 32;
    #pragma unroll
    for (int r2 = 0; r2 < 2; ++r2) {
      const int ci = r2 * 4 + w;
      const int row = ci * 16 + srow;
      const char* ga = (const char*)(Ab + (size_t)(rowBase + row) * LDK + k0) + sslot * 16;
      const char* gb = (const char*)(Bb + (size_t)(colBase + row) * LDK + k0) + sslot * 16;
      __builtin_amdgcn_global_load_lds((gv_t*)ga, (lv_t*)((char*)As + ci * 1024), 16, 0, 0);
      __builtin_amdgcn_global_load_lds((gv_t*)gb, (lv_t*)((char*)Bs + ci * 1024), 16, 0, 0);
    }
    __syncthreads();
    bf16x8 af[4], bfv[4];
    #pragma unroll
    for (int mi = 0; mi < 4; ++mi)
      af[mi] = *(const bf16x8*)((const char*)As + (wr * 64 + mi * 16 + lr) * 64 + lk * 16);
    #pragma unroll
    for (int ni = 0; ni < 4; ++ni)
      bfv[ni] = *(const bf16x8*)((const char*)Bs + (wc * 64 + ni * 16 + lr) * 64 + lk * 16);
    #pragma unroll
    for (int mi = 0; mi < 4; ++mi)
      #pragma unroll
      for (int ni = 0; ni < 4; ++ni)
        acc[mi][ni] = __builtin_amdgcn_mfma_f32_16x16x32_bf16(af[mi], bfv[ni], acc[mi][ni], 0, 0, 0);
    __syncthreads();
  }

  if constexpr (EPI == 0) {
    ushort_t* P = (ushort_t*)outPtr + (size_t)bz * oBatch;
    #pragma unroll
    for (int mi = 0; mi < 4; ++mi) {
      const int row0 = rowBase + wr * 64 + mi * 16 + lk * 4;
      #pragma unroll
      for (int ni = 0; ni < 4; ++ni) {
        const int col = colBase + wc * 64 + ni * 16 + lr;
        #pragma unroll
        for (int r = 0; r < 4; ++r)
          P[(size_t)(row0 + r) * NP + col] = f2b(acc[mi][ni][r] * scale);
      }
    }
  } else {
    float* O = (float*)outPtr;
    constexpr int OWN = Ww / PW;
    constexpr int OHW = (Hh / PH) * OWN;
    constexpr int PHPW = PH * PW;
    #pragma unroll
    for (int mi = 0; mi < 4; ++mi) {
      #pragma unroll
      for (int ni = 0; ni < 4; ++ni) {
        const int d = colBase + wc * 64 + ni * 16 + lr;
        const int c   = d >> ilog2c(PHPW);
        const int pyx = d & (PHPW - 1);
        const int py  = pyx >> ilog2c(PW);
        const int px  = pyx & (PW - 1);
        #pragma unroll
        for (int r = 0; r < 4; ++r) {
          const int q = rowBase + wr * 64 + mi * 16 + lk * 4 + r;
          const int t  = q >> ilog2c(OHW);
          const int rm = q & (OHW - 1);
          const int oh = rm >> ilog2c(OWN);
          const int ow = rm & (OWN - 1);
          size_t off = (((size_t)((bz * Tt + t) * Cc + CBASE + c)) << 12)
                     + ((oh * PH + py) << 6) + ow * PW + px;
          O[off] = acc[mi][ni][r];
        }
      }
    }
  }
}

// ---------------- row softmax over bf16 scores, in place ----------------
template<int NP>
__global__ __launch_bounds__(256) void softmax_rows(ushort_t* __restrict__ P) {
  constexpr int PER = NP / 256;    // elems per thread
  constexpr int CH  = NP / 1024;   // short4 chunks per thread
  ushort_t* row = P + (size_t)blockIdx.x * NP;
  const int tid = threadIdx.x;
  float v[PER];
  #pragma unroll
  for (int j = 0; j < CH; ++j) {
    short4v s = *(const short4v*)(row + j * 1024 + tid * 4);
    #pragma unroll
    for (int jj = 0; jj < 4; ++jj) v[4 * j + jj] = b2f((ushort_t)s[jj]);
  }
  float m = -1e30f;
  #pragma unroll
  for (int j = 0; j < PER; ++j) m = fmaxf(m, v[j]);
  #pragma unroll
  for (int o = 32; o >= 1; o >>= 1) m = fmaxf(m, __shfl_xor(m, o));
  __shared__ float redm[4];
  if ((tid & 63) == 0) redm[tid >> 6] = m;
  __syncthreads();
  m = fmaxf(fmaxf(redm[0], redm[1]), fmaxf(redm[2], redm[3]));
  float sum = 0.f;
  #pragma unroll
  for (int j = 0; j < PER; ++j) { v[j] = __expf(v[j] - m); sum += v[j]; }
  #pragma unroll
  for (int o = 32; o >= 1; o >>= 1) sum += __shfl_xor(sum, o);
  __shared__ float reds[4];
  if ((tid & 63) == 0) reds[tid >> 6] = sum;
  __syncthreads();
  sum = reds[0] + reds[1] + reds[2] + reds[3];
  const float inv = 1.0f / sum;
  #pragma unroll
  for (int j = 0; j < CH; ++j) {
    short4v o;
    #pragma unroll
    for (int jj = 0; jj < 4; ++jj) o[jj] = (short)f2b(v[4 * j + jj] * inv);
    *(short4v*)(row + j * 1024 + tid * 4) = o;
  }
}

extern "C" void kernel_launch(void* const* d_in, const int* in_sizes, int n_in,
                              void* d_out, int out_size, void* d_ws, size_t ws_size,
                              hipStream_t stream) {
  const float* q = (const float*)d_in[0];
  const float* k = (const float*)d_in[1];
  const float* v = (const float*)d_in[2];
  // ws layout (bf16 elems): A region (Q tokens, later V^T), B region (K tokens), P region
  ushort_t* wsA = (ushort_t*)d_ws;
  ushort_t* wsB = wsA + (size_t)33554432;          // 64 MiB in
  ushort_t* wsP = wsB + (size_t)33554432;          // 128 MiB in; P = 71.3 MB
  const size_t P1OFF = 16777216;                   // patch-1 offset within A/B regions (elems)
  const size_t PP1   = 2097152;                    // patch-1 offset within P region (elems)

  // tokenize Q, K (both patches)
  tok_qk<8, 8, 0,   1024><<<8192,  256, 0, stream>>>(q, wsA);
  tok_qk<4, 4, 128, 4096><<<16384, 256, 0, stream>>>(q, wsA + P1OFF);
  tok_qk<8, 8, 0,   1024><<<8192,  256, 0, stream>>>(k, wsB);
  tok_qk<4, 4, 128, 4096><<<16384, 256, 0, stream>>>(k, wsB + P1OFF);

  // S = Q K^T * 1/sqrt(D)  (bf16 out)
  gemm_nt<0, 256, 8192, 1024, 8, 8, 0><<<dim3(8, 8, 2), 256, 0, stream>>>(
      wsA, wsB, (size_t)1024 * 8192, (size_t)1024 * 8192, wsP, (size_t)1024 * 1024,
      0.011048543456039806f);
  gemm_nt<0, 64, 2048, 4096, 4, 4, 128><<<dim3(32, 32, 2), 256, 0, stream>>>(
      wsA + P1OFF, wsB + P1OFF, (size_t)4096 * 2048, (size_t)4096 * 2048, wsP + PP1,
      (size_t)4096 * 4096, 0.022097086912079612f);

  // softmax rows
  softmax_rows<1024><<<2048, 256, 0, stream>>>(wsP);
  softmax_rows<4096><<<8192, 256, 0, stream>>>(wsP + PP1);

  // tokenize V transposed into A region (Q tokens no longer needed)
  tok_vt<8, 8, 0,   1024><<<8192,  256, 0, stream>>>(v, wsA);
  tok_vt<4, 4, 128, 4096><<<16384, 256, 0, stream>>>(v, wsA + P1OFF);

  // O = P * V  -> scatter fp32 into d_out (from_tokens layout)
  gemm_nt<1, 32, 1024, 1024, 8, 8, 0><<<dim3(64, 8, 2), 256, 0, stream>>>(
      wsP, wsA, (size_t)1024 * 1024, (size_t)8192 * 1024, d_out, 0, 1.0f);
  gemm_nt<1, 128, 4096, 4096, 4, 4, 128><<<dim3(16, 32, 2), 256, 0, stream>>>(
      wsP + PP1, wsA + P1OFF, (size_t)4096 * 4096, (size_t)2048 * 4096, d_out, 0, 1.0f);
}

// Round 2
// 781.863 us; speedup vs baseline: 1.1512x; 1.1512x over previous
//
#include <hip/hip_runtime.h>
#include <hip/hip_bf16.h>
#include <stdint.h>

typedef unsigned short ushort_t;
typedef unsigned int uint_t;

typedef __bf16 bf16x8 __attribute__((ext_vector_type(8)));
typedef float f32x4 __attribute__((ext_vector_type(4)));
typedef short short4v __attribute__((ext_vector_type(4)));

typedef const __attribute__((address_space(1))) void gv_t;
typedef __attribute__((address_space(3))) void lv_t;

__device__ __forceinline__ ushort_t f2b(float f) {
  uint_t u = __builtin_bit_cast(uint_t, f);
  u += 0x7FFFu + ((u >> 16) & 1u);   // round-to-nearest-even
  return (ushort_t)(u >> 16);
}
__device__ __forceinline__ float b2f(ushort_t s) {
  return __builtin_bit_cast(float, (uint_t)s << 16);
}
constexpr int ilog2c(int x) { return x <= 1 ? 0 : 1 + ilog2c(x >> 1); }

constexpr int Tt = 16, Cc = 256, Hh = 64, Ww = 64, DKc = 128;

// ---------------- tokenize Q/K: (B*T,128,H,W) slice -> (b, n, d) bf16 row-major ----------------
template<int PH, int PW, int CBASE, int NP>
__global__ __launch_bounds__(256) void tok_qk(const float* __restrict__ src, ushort_t* __restrict__ dst) {
  constexpr int OHN = Hh / PH, OWN = Ww / PW, DP = DKc * PH * PW, OHW = OHN * OWN;
  const int id = blockIdx.x * 256 + threadIdx.x;
  const int py = id & (PH - 1);
  const int c  = (id >> ilog2c(PH)) & (DKc - 1);
  const int n  = (id >> (ilog2c(PH) + 7)) & (NP - 1);
  const int b  = id >> (ilog2c(PH) + 7 + ilog2c(NP));
  const int t  = n >> ilog2c(OHW);
  const int rem = n & (OHW - 1);
  const int oh = rem >> ilog2c(OWN);
  const int ow = rem & (OWN - 1);
  const float* s = src + (((size_t)((b * Tt + t) * Cc + CBASE + c)) << 12)
                       + ((oh * PH + py) << 6) + ow * PW;
  ushort_t* d = dst + (size_t)(b * NP + n) * DP + (c * PH + py) * PW;
  float4 f0 = *(const float4*)s;
  short4v o0; o0[0] = f2b(f0.x); o0[1] = f2b(f0.y); o0[2] = f2b(f0.z); o0[3] = f2b(f0.w);
  *(short4v*)d = o0;
  if constexpr (PW == 8) {
    float4 f1 = *(const float4*)(s + 4);
    short4v o1; o1[0] = f2b(f1.x); o1[1] = f2b(f1.y); o1[2] = f2b(f1.z); o1[3] = f2b(f1.w);
    *(short4v*)(d + 4) = o1;
  }
}

// ---------------- tokenize V transposed: -> (b, d, n) bf16 row-major ----------------
template<int PH, int PW, int CBASE, int NP>
__global__ __launch_bounds__(256) void tok_vt(const float* __restrict__ src, ushort_t* __restrict__ dst) {
  constexpr int OHN = Hh / PH, OWN = Ww / PW, DP = DKc * PH * PW;
  constexpr int CH = PW, NCH = OWN / CH;
  const int id  = blockIdx.x * 256 + threadIdx.x;
  const int owc = id & (NCH - 1);
  const int oh  = (id >> ilog2c(NCH)) & (OHN - 1);
  const int t   = (id >> (ilog2c(NCH) + ilog2c(OHN))) & (Tt - 1);
  const int dd  = (id >> (ilog2c(NCH) + ilog2c(OHN) + 4)) & (DP - 1);
  const int b   = id >> (ilog2c(NCH) + ilog2c(OHN) + 4 + ilog2c(DP));
  const int c   = dd >> ilog2c(PH * PW);
  const int py  = (dd >> ilog2c(PW)) & (PH - 1);
  const int px  = dd & (PW - 1);
  const float* s = src + (((size_t)((b * Tt + t) * Cc + CBASE + c)) << 12)
                       + ((oh * PH + py) << 6) + px;
  const int n0 = (t * OHN + oh) * OWN + owc * CH;
  ushort_t* d = dst + (size_t)(b * DP + dd) * NP + n0;
  short4v o;
  #pragma unroll
  for (int j = 0; j < 4; ++j) o[j] = f2b(s[(owc * CH + j) * PW]);
  *(short4v*)d = o;
  if constexpr (CH == 8) {
    short4v o2;
    #pragma unroll
    for (int j = 0; j < 4; ++j) o2[j] = f2b(s[(owc * CH + 4 + j) * PW]);
    *(short4v*)(d + 4) = o2;
  }
}

__device__ __forceinline__ void waitvm4() { asm volatile("s_waitcnt vmcnt(4)" ::: "memory"); }
__device__ __forceinline__ void waitvm0() { asm volatile("s_waitcnt vmcnt(0)" ::: "memory"); }

// ---------------- 3-deep pipelined NT GEMM: C(MxN) = A(MxK)*B(NxK)^T, bf16 MFMA ----------------
// EPI 0: bf16 scores*scale -> P (row-major, ld=NP)
// EPI 1: fp32 scatter to d_out via from_tokens mapping
// EPI 2: fp32 linear partial (split-K), layout [ks][batch][M][NP]
template<int WM_, int WN_, int MI_, int NI_, int EPI, int KSPLIT,
         int NP, int PH, int PW, int CBASE>
__global__ __launch_bounds__(WM_*WN_*64, 2)
void gemm_pipe(const ushort_t* __restrict__ A, const ushort_t* __restrict__ B,
               size_t aBatch, size_t bBatch, int ldk, int nt,
               void* __restrict__ outPtr, size_t oBatch, float scale) {
  constexpr int BM = WM_ * MI_ * 16, BN = WN_ * NI_ * 16;
  constexpr int T = WM_ * WN_ * 64, NW = T / 64;
  constexpr int RA = (BM * 64) / (T * 16), RB = (BN * 64) / (T * 16);
  static_assert(RA + RB == 4, "vmcnt hardcoded to 4");
  __shared__ ushort_t As[3 * BM * 32];
  __shared__ ushort_t Bs[3 * BN * 32];

  const int tid = threadIdx.x;
  const int w = tid >> 6, l = tid & 63;
  const int wm = w / WN_, wn = w % WN_;
  const int lr = l & 15, lk = l >> 4;
  const int srow = l >> 2, sslot = l & 3;

  // XCD-aware swizzle of linear block id (grid size always a multiple of 8)
  const int gx = gridDim.x, gy = gridDim.y, gz = gridDim.z;
  int id = (blockIdx.z * gy + blockIdx.y) * gx + blockIdx.x;
  const int cpx = (gx * gy * gz) >> 3;
  id = (id & 7) * cpx + (id >> 3);
  const int bx = id % gx;
  const int rst = id / gx;
  const int by = rst % gy;
  const int bz = rst / gy;

  int batch = bz, ks = 0;
  if constexpr (KSPLIT > 1) { batch = bz / KSPLIT; ks = bz - batch * KSPLIT; }

  const int rowBase = by * BM, colBase = bx * BN;
  const ushort_t* Ab = A + (size_t)batch * aBatch + (size_t)ks * nt * 32;
  const ushort_t* Bb = B + (size_t)batch * bBatch + (size_t)ks * nt * 32;

  f32x4 acc[MI_][NI_] = {};

  // stage K-tile kt into buffer buf; LDS linear dest, XOR-preswizzled global source
  auto stage = [&](int buf, int kt) {
    const int k0 = kt * 32;
#pragma unroll
    for (int r = 0; r < RA; ++r) {
      const int ci = r * NW + w;
      const int row = ci * 16 + srow;
      const int sl = sslot ^ (row & 3);
      const ushort_t* g = Ab + (size_t)(rowBase + row) * ldk + k0 + sl * 8;
      __builtin_amdgcn_global_load_lds((gv_t*)g, (lv_t*)((char*)As + buf * (BM * 64) + ci * 1024), 16, 0, 0);
    }
#pragma unroll
    for (int r = 0; r < RB; ++r) {
      const int ci = r * NW + w;
      const int row = ci * 16 + srow;
      const int sl = sslot ^ (row & 3);
      const ushort_t* g = Bb + (size_t)(colBase + row) * ldk + k0 + sl * 8;
      __builtin_amdgcn_global_load_lds((gv_t*)g, (lv_t*)((char*)Bs + buf * (BN * 64) + ci * 1024), 16, 0, 0);
    }
  };

  auto compute = [&](int buf) {
    const ushort_t* Ap = As + buf * (BM * 32);
    const ushort_t* Bp = Bs + buf * (BN * 32);
    bf16x8 af[MI_], bfv[NI_];
#pragma unroll
    for (int mi = 0; mi < MI_; ++mi) {
      const int row = wm * (MI_ * 16) + mi * 16 + lr;
      af[mi] = *(const bf16x8*)(Ap + row * 32 + ((lk ^ (row & 3)) << 3));
    }
#pragma unroll
    for (int ni = 0; ni < NI_; ++ni) {
      const int row = wn * (NI_ * 16) + ni * 16 + lr;
      bfv[ni] = *(const bf16x8*)(Bp + row * 32 + ((lk ^ (row & 3)) << 3));
    }
    __builtin_amdgcn_s_setprio(1);
#pragma unroll
    for (int mi = 0; mi < MI_; ++mi)
#pragma unroll
      for (int ni = 0; ni < NI_; ++ni)
        acc[mi][ni] = __builtin_amdgcn_mfma_f32_16x16x32_bf16(af[mi], bfv[ni], acc[mi][ni], 0, 0, 0);
    __builtin_amdgcn_s_setprio(0);
  };

  // prologue: tiles 0,1 in flight; wait tile 0 (tile 1 stays outstanding)
  stage(0, 0);
  stage(1, 1);
  waitvm4();
  __builtin_amdgcn_s_barrier();

  int b0 = 0;
  for (int t = 0; t < nt - 2; ++t) {
    int b2 = b0 + 2; if (b2 >= 3) b2 -= 3;
    stage(b2, t + 2);           // issue before reads (T3); lands into non-read buffer
    compute(b0);
    waitvm4();                  // counted: t+1 landed, t+2 stays in flight (T4)
    __builtin_amdgcn_s_barrier();
    b0 = (b0 == 2) ? 0 : b0 + 1;
  }
  compute(b0);                  // tile nt-2
  waitvm0();
  __builtin_amdgcn_s_barrier();
  compute((b0 == 2) ? 0 : b0 + 1);  // tile nt-1

  if constexpr (EPI == 0) {
    ushort_t* P = (ushort_t*)outPtr + (size_t)batch * oBatch;
#pragma unroll
    for (int mi = 0; mi < MI_; ++mi) {
      const int row0 = rowBase + wm * (MI_ * 16) + mi * 16 + lk * 4;
#pragma unroll
      for (int ni = 0; ni < NI_; ++ni) {
        const int col = colBase + wn * (NI_ * 16) + ni * 16 + lr;
#pragma unroll
        for (int r = 0; r < 4; ++r)
          P[(size_t)(row0 + r) * NP + col] = f2b(acc[mi][ni][r] * scale);
      }
    }
  } else if constexpr (EPI == 1) {
    float* O = (float*)outPtr;
    constexpr int OWN = Ww / PW;
    constexpr int OHW = (Hh / PH) * OWN;
    constexpr int PHPW = PH * PW;
#pragma unroll
    for (int mi = 0; mi < MI_; ++mi) {
#pragma unroll
      for (int ni = 0; ni < NI_; ++ni) {
        const int d = colBase + wn * (NI_ * 16) + ni * 16 + lr;
        const int c   = d >> ilog2c(PHPW);
        const int pyx = d & (PHPW - 1);
        const int py  = pyx >> ilog2c(PW);
        const int px  = pyx & (PW - 1);
#pragma unroll
        for (int r = 0; r < 4; ++r) {
          const int qq = rowBase + wm * (MI_ * 16) + mi * 16 + lk * 4 + r;
          const int tt = qq >> ilog2c(OHW);
          const int rm = qq & (OHW - 1);
          const int oh = rm >> ilog2c(OWN);
          const int ow = rm & (OWN - 1);
          size_t off = (((size_t)((batch * Tt + tt) * Cc + CBASE + c)) << 12)
                     + ((oh * PH + py) << 6) + ow * PW + px;
          O[off] = acc[mi][ni][r];
        }
      }
    }
  } else {
    const int nb = gz / KSPLIT;
    float* O = (float*)outPtr + ((size_t)ks * nb + batch) * oBatch;
#pragma unroll
    for (int mi = 0; mi < MI_; ++mi) {
      const int row0 = rowBase + wm * (MI_ * 16) + mi * 16 + lk * 4;
#pragma unroll
      for (int ni = 0; ni < NI_; ++ni) {
        const int col = colBase + wn * (NI_ * 16) + ni * 16 + lr;
#pragma unroll
        for (int r = 0; r < 4; ++r)
          O[(size_t)(row0 + r) * NP + col] = acc[mi][ni][r] * scale;
      }
    }
  }
}

// ---------------- row softmax over bf16 scores, in place ----------------
template<int NP>
__global__ __launch_bounds__(256) void softmax_rows(ushort_t* __restrict__ P) {
  constexpr int PER = NP / 256;
  constexpr int CH  = NP / 1024;
  ushort_t* row = P + (size_t)blockIdx.x * NP;
  const int tid = threadIdx.x;
  float v[PER];
  #pragma unroll
  for (int j = 0; j < CH; ++j) {
    short4v s = *(const short4v*)(row + j * 1024 + tid * 4);
    #pragma unroll
    for (int jj = 0; jj < 4; ++jj) v[4 * j + jj] = b2f((ushort_t)s[jj]);
  }
  float m = -1e30f;
  #pragma unroll
  for (int j = 0; j < PER; ++j) m = fmaxf(m, v[j]);
  #pragma unroll
  for (int o = 32; o >= 1; o >>= 1) m = fmaxf(m, __shfl_xor(m, o));
  __shared__ float redm[4];
  if ((tid & 63) == 0) redm[tid >> 6] = m;
  __syncthreads();
  m = fmaxf(fmaxf(redm[0], redm[1]), fmaxf(redm[2], redm[3]));
  float sum = 0.f;
  #pragma unroll
  for (int j = 0; j < PER; ++j) { v[j] = __expf(v[j] - m); sum += v[j]; }
  #pragma unroll
  for (int o = 32; o >= 1; o >>= 1) sum += __shfl_xor(sum, o);
  __shared__ float reds[4];
  if ((tid & 63) == 0) reds[tid >> 6] = sum;
  __syncthreads();
  sum = reds[0] + reds[1] + reds[2] + reds[3];
  const float inv = 1.0f / sum;
  #pragma unroll
  for (int j = 0; j < CH; ++j) {
    short4v o;
    #pragma unroll
    for (int jj = 0; jj < 4; ++jj) o[jj] = (short)f2b(v[4 * j + jj] * inv);
    *(short4v*)(row + j * 1024 + tid * 4) = o;
  }
}

// ---------------- combine 2 fp32 split-K partials + softmax -> bf16 P (patch 0, NP=1024) ----------------
__global__ __launch_bounds__(256) void softmax_combine_p0(const float* __restrict__ part,
                                                          ushort_t* __restrict__ P) {
  const int tid = threadIdx.x;
  const float* r0 = part + (size_t)blockIdx.x * 1024 + tid * 4;
  float4 a = *(const float4*)r0;
  float4 b = *(const float4*)(r0 + 2097152);
  float v[4] = {a.x + b.x, a.y + b.y, a.z + b.z, a.w + b.w};
  float m = fmaxf(fmaxf(v[0], v[1]), fmaxf(v[2], v[3]));
  #pragma unroll
  for (int o = 32; o >= 1; o >>= 1) m = fmaxf(m, __shfl_xor(m, o));
  __shared__ float redm[4], reds[4];
  if ((tid & 63) == 0) redm[tid >> 6] = m;
  __syncthreads();
  m = fmaxf(fmaxf(redm[0], redm[1]), fmaxf(redm[2], redm[3]));
  float sum = 0.f;
  #pragma unroll
  for (int j = 0; j < 4; ++j) { v[j] = __expf(v[j] - m); sum += v[j]; }
  #pragma unroll
  for (int o = 32; o >= 1; o >>= 1) sum += __shfl_xor(sum, o);
  if ((tid & 63) == 0) reds[tid >> 6] = sum;
  __syncthreads();
  sum = reds[0] + reds[1] + reds[2] + reds[3];
  const float inv = 1.0f / sum;
  short4v o4;
  #pragma unroll
  for (int j = 0; j < 4; ++j) o4[j] = (short)f2b(v[j] * inv);
  *(short4v*)(P + (size_t)blockIdx.x * 1024 + tid * 4) = o4;
}

extern "C" void kernel_launch(void* const* d_in, const int* in_sizes, int n_in,
                              void* d_out, int out_size, void* d_ws, size_t ws_size,
                              hipStream_t stream) {
  const float* q = (const float*)d_in[0];
  const float* k = (const float*)d_in[1];
  const float* v = (const float*)d_in[2];
  ushort_t* wsA = (ushort_t*)d_ws;
  ushort_t* wsB = wsA + (size_t)33554432;          // 64 MiB in
  ushort_t* wsP = wsB + (size_t)33554432;          // 128 MiB in
  const size_t P1OFF = 16777216;                   // patch-1 offset within A/B regions (elems)
  const size_t PP1   = 2097152;                    // patch-1 offset within P region (elems)
  float* part = (float*)(wsP + PP1);               // QK-p0 split-K partials (16 MiB), reused by P p1 later

  // tokenize Q, K
  tok_qk<8, 8, 0,   1024><<<8192,  256, 0, stream>>>(q, wsA);
  tok_qk<4, 4, 128, 4096><<<16384, 256, 0, stream>>>(q, wsA + P1OFF);
  tok_qk<8, 8, 0,   1024><<<8192,  256, 0, stream>>>(k, wsB);
  tok_qk<4, 4, 128, 4096><<<16384, 256, 0, stream>>>(k, wsB + P1OFF);

  // QK p0: 128^2 tile, split-K=2 -> fp32 partials; then fused combine+softmax
  gemm_pipe<2, 2, 4, 4, 2, 2, 1024, 1, 1, 0><<<dim3(8, 8, 4), 256, 0, stream>>>(
      wsA, wsB, (size_t)1024 * 8192, (size_t)1024 * 8192, 8192, 128,
      part, (size_t)1048576, 0.011048543456039806f);
  softmax_combine_p0<<<2048, 256, 0, stream>>>(part, wsP);

  // QK p1: 256^2 tile (overwrites partial region AFTER combine consumed it)
  gemm_pipe<2, 4, 8, 4, 0, 1, 4096, 1, 1, 0><<<dim3(16, 16, 2), 512, 0, stream>>>(
      wsA + P1OFF, wsB + P1OFF, (size_t)4096 * 2048, (size_t)4096 * 2048, 2048, 64,
      wsP + PP1, (size_t)4096 * 4096, 0.022097086912079612f);
  softmax_rows<4096><<<8192, 256, 0, stream>>>(wsP + PP1);

  // tokenize V transposed into A region (Q tokens no longer needed)
  tok_vt<8, 8, 0,   1024><<<8192,  256, 0, stream>>>(v, wsA);
  tok_vt<4, 4, 128, 4096><<<16384, 256, 0, stream>>>(v, wsA + P1OFF);

  // O = P * V -> scatter fp32 into d_out
  gemm_pipe<2, 4, 8, 4, 1, 1, 0, 8, 8, 0><<<dim3(32, 4, 2), 512, 0, stream>>>(
      wsP, wsA, (size_t)1024 * 1024, (size_t)8192 * 1024, 1024, 32, d_out, 0, 1.0f);
  gemm_pipe<2, 4, 8, 4, 1, 1, 0, 4, 4, 128><<<dim3(8, 16, 2), 512, 0, stream>>>(
      wsP + PP1, wsA + P1OFF, (size_t)4096 * 4096, (size_t)2048 * 4096, 4096, 128, d_out, 0, 1.0f);
}

// Round 3
// 722.844 us; speedup vs baseline: 1.2452x; 1.0816x over previous
//
#include <hip/hip_runtime.h>
#include <hip/hip_bf16.h>
#include <stdint.h>

typedef unsigned short ushort_t;
typedef unsigned int uint_t;

typedef __bf16 bf16x8 __attribute__((ext_vector_type(8)));
typedef float f32x4 __attribute__((ext_vector_type(4)));
typedef short short4v __attribute__((ext_vector_type(4)));

typedef const __attribute__((address_space(1))) void gv_t;
typedef __attribute__((address_space(3))) void lv_t;

__device__ __forceinline__ ushort_t f2b(float f) {
  uint_t u = __builtin_bit_cast(uint_t, f);
  u += 0x7FFFu + ((u >> 16) & 1u);   // round-to-nearest-even
  return (ushort_t)(u >> 16);
}
__device__ __forceinline__ float b2f(ushort_t s) {
  return __builtin_bit_cast(float, (uint_t)s << 16);
}
constexpr int ilog2c(int x) { return x <= 1 ? 0 : 1 + ilog2c(x >> 1); }

constexpr int Tt = 16, Cc = 256, Hh = 64, Ww = 64, DKc = 128;

// ---------------- tokenize Q/K: (B*T,128,H,W) slice -> (b, n, d) bf16 row-major ----------------
template<int PH, int PW, int CBASE, int NP>
__global__ __launch_bounds__(256) void tok_qk(const float* __restrict__ src, ushort_t* __restrict__ dst) {
  constexpr int OHN = Hh / PH, OWN = Ww / PW, DP = DKc * PH * PW, OHW = OHN * OWN;
  const int id = blockIdx.x * 256 + threadIdx.x;
  const int py = id & (PH - 1);
  const int c  = (id >> ilog2c(PH)) & (DKc - 1);
  const int n  = (id >> (ilog2c(PH) + 7)) & (NP - 1);
  const int b  = id >> (ilog2c(PH) + 7 + ilog2c(NP));
  const int t  = n >> ilog2c(OHW);
  const int rem = n & (OHW - 1);
  const int oh = rem >> ilog2c(OWN);
  const int ow = rem & (OWN - 1);
  const float* s = src + (((size_t)((b * Tt + t) * Cc + CBASE + c)) << 12)
                       + ((oh * PH + py) << 6) + ow * PW;
  ushort_t* d = dst + (size_t)(b * NP + n) * DP + (c * PH + py) * PW;
  float4 f0 = *(const float4*)s;
  short4v o0; o0[0] = f2b(f0.x); o0[1] = f2b(f0.y); o0[2] = f2b(f0.z); o0[3] = f2b(f0.w);
  *(short4v*)d = o0;
  if constexpr (PW == 8) {
    float4 f1 = *(const float4*)(s + 4);
    short4v o1; o1[0] = f2b(f1.x); o1[1] = f2b(f1.y); o1[2] = f2b(f1.z); o1[3] = f2b(f1.w);
    *(short4v*)(d + 4) = o1;
  }
}

// ---------------- tokenize V transposed: -> (b, d, n) bf16 row-major ----------------
template<int PH, int PW, int CBASE, int NP>
__global__ __launch_bounds__(256) void tok_vt(const float* __restrict__ src, ushort_t* __restrict__ dst) {
  constexpr int OHN = Hh / PH, OWN = Ww / PW, DP = DKc * PH * PW;
  constexpr int CH = PW, NCH = OWN / CH;
  const int id  = blockIdx.x * 256 + threadIdx.x;
  const int owc = id & (NCH - 1);
  const int oh  = (id >> ilog2c(NCH)) & (OHN - 1);
  const int t   = (id >> (ilog2c(NCH) + ilog2c(OHN))) & (Tt - 1);
  const int dd  = (id >> (ilog2c(NCH) + ilog2c(OHN) + 4)) & (DP - 1);
  const int b   = id >> (ilog2c(NCH) + ilog2c(OHN) + 4 + ilog2c(DP));
  const int c   = dd >> ilog2c(PH * PW);
  const int py  = (dd >> ilog2c(PW)) & (PH - 1);
  const int px  = dd & (PW - 1);
  const float* s = src + (((size_t)((b * Tt + t) * Cc + CBASE + c)) << 12)
                       + ((oh * PH + py) << 6) + px;
  const int n0 = (t * OHN + oh) * OWN + owc * CH;
  ushort_t* d = dst + (size_t)(b * DP + dd) * NP + n0;
  short4v o;
  #pragma unroll
  for (int j = 0; j < 4; ++j) o[j] = f2b(s[(owc * CH + j) * PW]);
  *(short4v*)d = o;
  if constexpr (CH == 8) {
    short4v o2;
    #pragma unroll
    for (int j = 0; j < 4; ++j) o2[j] = f2b(s[(owc * CH + 4 + j) * PW]);
    *(short4v*)(d + 4) = o2;
  }
}

__device__ __forceinline__ void waitvm4() { asm volatile("s_waitcnt vmcnt(4)" ::: "memory"); }
__device__ __forceinline__ void waitvm0() { asm volatile("s_waitcnt vmcnt(0)" ::: "memory"); }

// ---------------- 3-deep pipelined, 2-phase NT GEMM: C(MxN)=A(MxK)*B(NxK)^T, 256x256 tile ----------------
// EPI 0: bf16 scores*scale -> P (row-major, ld=NP)
// EPI 1: fp32 scatter to d_out via from_tokens mapping
// EPI 2: fp32 linear partial (split-K), layout [ks][batch][M][NP]
template<int EPI, int KSPLIT, int NP, int PH, int PW, int CBASE>
__global__ __launch_bounds__(512, 2)
void gemm_pipe(const ushort_t* __restrict__ A, const ushort_t* __restrict__ B,
               size_t aBatch, size_t bBatch, int ldk, int nt,
               void* __restrict__ outPtr, size_t oBatch, float scale) {
  constexpr int WM_ = 2, WN_ = 4, MI_ = 8, NI_ = 4;
  constexpr int BM = WM_ * MI_ * 16, BN = WN_ * NI_ * 16;   // 256 x 256
  constexpr int NW = 8;
  __shared__ ushort_t As[3 * BM * 32];
  __shared__ ushort_t Bs[3 * BN * 32];

  const int tid = threadIdx.x;
  const int w = tid >> 6, l = tid & 63;
  const int wm = w >> 2, wn = w & 3;
  const int lr = l & 15, lk = l >> 4;
  const int srow = l >> 2, sslot = l & 3;

  // XCD-aware swizzle of linear block id (grid size always a multiple of 8)
  const int gx = gridDim.x, gy = gridDim.y, gz = gridDim.z;
  int id = (blockIdx.z * gy + blockIdx.y) * gx + blockIdx.x;
  const int cpx = (gx * gy * gz) >> 3;
  id = (id & 7) * cpx + (id >> 3);
  const int bx = id % gx;
  const int rst = id / gx;
  const int by = rst % gy;
  const int bz = rst / gy;

  int batch = bz, ks = 0;
  if constexpr (KSPLIT > 1) { batch = bz / KSPLIT; ks = bz - batch * KSPLIT; }

  const int rowBase = by * BM, colBase = bx * BN;
  const ushort_t* Ab = A + (size_t)batch * aBatch + (size_t)ks * nt * 32;
  const ushort_t* Bb = B + (size_t)batch * bBatch + (size_t)ks * nt * 32;

  f32x4 acc[MI_][NI_] = {};

  // stage halves: LDS linear dest, inverse-swizzled global source (slot ^= (row>>1)&3)
  auto stageA = [&](int buf, int kt) {
    const int k0 = kt * 32;
#pragma unroll
    for (int r = 0; r < 2; ++r) {
      const int ci = r * NW + w;
      const int row = ci * 16 + srow;
      const int sl = sslot ^ ((row >> 1) & 3);
      const ushort_t* g = Ab + (size_t)(rowBase + row) * ldk + k0 + sl * 8;
      __builtin_amdgcn_global_load_lds((gv_t*)g, (lv_t*)((char*)As + buf * (BM * 64) + ci * 1024), 16, 0, 0);
    }
  };
  auto stageB = [&](int buf, int kt) {
    const int k0 = kt * 32;
#pragma unroll
    for (int r = 0; r < 2; ++r) {
      const int ci = r * NW + w;
      const int row = ci * 16 + srow;
      const int sl = sslot ^ ((row >> 1) & 3);
      const ushort_t* g = Bb + (size_t)(colBase + row) * ldk + k0 + sl * 8;
      __builtin_amdgcn_global_load_lds((gv_t*)g, (lv_t*)((char*)Bs + buf * (BN * 64) + ci * 1024), 16, 0, 0);
    }
  };

  auto readA = [&](const ushort_t* Ap, int half, bf16x8* af) {
#pragma unroll
    for (int mi = 0; mi < 4; ++mi) {
      const int row = wm * (MI_ * 16) + (half * 4 + mi) * 16 + lr;
      af[mi] = *(const bf16x8*)(Ap + row * 32 + ((lk ^ ((row >> 1) & 3)) << 3));
    }
  };
  auto readB = [&](const ushort_t* Bp, bf16x8* bv) {
#pragma unroll
    for (int ni = 0; ni < 4; ++ni) {
      const int row = wn * (NI_ * 16) + ni * 16 + lr;
      bv[ni] = *(const bf16x8*)(Bp + row * 32 + ((lk ^ ((row >> 1) & 3)) << 3));
    }
  };

  // prologue: tiles 0,1 in flight; wait tile 0 (tile 1 stays outstanding)
  stageA(0, 0); stageB(0, 0);
  stageA(1, 1); stageB(1, 1);
  waitvm4();
  __builtin_amdgcn_s_barrier();

  int b0 = 0;
  for (int t = 0; t < nt - 2; ++t) {
    int b2 = b0 + 2; if (b2 >= 3) b2 -= 3;
    const ushort_t* Ap = As + b0 * (BM * 32);
    const ushort_t* Bp = Bs + b0 * (BN * 32);
    bf16x8 a0[4], a1[4], bv[4];
    // ---- phase A: read half-0 frags + all B, issue A-stage of t+2, MFMA half 0 ----
    readA(Ap, 0, a0);
    readB(Bp, bv);
    stageA(b2, t + 2);
    __builtin_amdgcn_sched_barrier(0);
    __builtin_amdgcn_s_barrier();
    __builtin_amdgcn_s_setprio(1);
#pragma unroll
    for (int mi = 0; mi < 4; ++mi)
#pragma unroll
      for (int ni = 0; ni < 4; ++ni)
        acc[mi][ni] = __builtin_amdgcn_mfma_f32_16x16x32_bf16(a0[mi], bv[ni], acc[mi][ni], 0, 0, 0);
    __builtin_amdgcn_s_setprio(0);
    __builtin_amdgcn_sched_barrier(0);
    __builtin_amdgcn_s_barrier();
    // ---- phase B: read half-1 frags, issue B-stage of t+2, MFMA half 1 ----
    readA(Ap, 1, a1);
    stageB(b2, t + 2);
    __builtin_amdgcn_sched_barrier(0);
    __builtin_amdgcn_s_barrier();
    __builtin_amdgcn_s_setprio(1);
#pragma unroll
    for (int mi = 0; mi < 4; ++mi)
#pragma unroll
      for (int ni = 0; ni < 4; ++ni)
        acc[4 + mi][ni] = __builtin_amdgcn_mfma_f32_16x16x32_bf16(a1[mi], bv[ni], acc[4 + mi][ni], 0, 0, 0);
    __builtin_amdgcn_s_setprio(0);
    waitvm4();                  // counted: t+1 landed, t+2 stays in flight
    __builtin_amdgcn_sched_barrier(0);
    __builtin_amdgcn_s_barrier();
    b0 = (b0 == 2) ? 0 : b0 + 1;
  }
  // tail: tiles nt-2, nt-1 (no staging)
  {
    const ushort_t* Ap = As + b0 * (BM * 32);
    const ushort_t* Bp = Bs + b0 * (BN * 32);
    bf16x8 a0[4], a1[4], bv[4];
    readA(Ap, 0, a0); readA(Ap, 1, a1); readB(Bp, bv);
#pragma unroll
    for (int mi = 0; mi < 4; ++mi)
#pragma unroll
      for (int ni = 0; ni < 4; ++ni) {
        acc[mi][ni] = __builtin_amdgcn_mfma_f32_16x16x32_bf16(a0[mi], bv[ni], acc[mi][ni], 0, 0, 0);
        acc[4 + mi][ni] = __builtin_amdgcn_mfma_f32_16x16x32_bf16(a1[mi], bv[ni], acc[4 + mi][ni], 0, 0, 0);
      }
    waitvm0();
    __builtin_amdgcn_s_barrier();
    const int b1 = (b0 == 2) ? 0 : b0 + 1;
    const ushort_t* Ap1 = As + b1 * (BM * 32);
    const ushort_t* Bp1 = Bs + b1 * (BN * 32);
    readA(Ap1, 0, a0); readA(Ap1, 1, a1); readB(Bp1, bv);
#pragma unroll
    for (int mi = 0; mi < 4; ++mi)
#pragma unroll
      for (int ni = 0; ni < 4; ++ni) {
        acc[mi][ni] = __builtin_amdgcn_mfma_f32_16x16x32_bf16(a0[mi], bv[ni], acc[mi][ni], 0, 0, 0);
        acc[4 + mi][ni] = __builtin_amdgcn_mfma_f32_16x16x32_bf16(a1[mi], bv[ni], acc[4 + mi][ni], 0, 0, 0);
      }
  }

  if constexpr (EPI == 0) {
    ushort_t* P = (ushort_t*)outPtr + (size_t)batch * oBatch;
#pragma unroll
    for (int mi = 0; mi < MI_; ++mi) {
      const int row0 = rowBase + wm * (MI_ * 16) + mi * 16 + lk * 4;
#pragma unroll
      for (int ni = 0; ni < NI_; ++ni) {
        const int col = colBase + wn * (NI_ * 16) + ni * 16 + lr;
#pragma unroll
        for (int r = 0; r < 4; ++r)
          P[(size_t)(row0 + r) * NP + col] = f2b(acc[mi][ni][r] * scale);
      }
    }
  } else if constexpr (EPI == 1) {
    float* O = (float*)outPtr;
    constexpr int OWN = Ww / PW;
    constexpr int OHW = (Hh / PH) * OWN;
    constexpr int PHPW = PH * PW;
#pragma unroll
    for (int mi = 0; mi < MI_; ++mi) {
#pragma unroll
      for (int ni = 0; ni < NI_; ++ni) {
        const int d = colBase + wn * (NI_ * 16) + ni * 16 + lr;
        const int c   = d >> ilog2c(PHPW);
        const int pyx = d & (PHPW - 1);
        const int py  = pyx >> ilog2c(PW);
        const int px  = pyx & (PW - 1);
#pragma unroll
        for (int r = 0; r < 4; ++r) {
          const int qq = rowBase + wm * (MI_ * 16) + mi * 16 + lk * 4 + r;
          const int tt = qq >> ilog2c(OHW);
          const int rm = qq & (OHW - 1);
          const int oh = rm >> ilog2c(OWN);
          const int ow = rm & (OWN - 1);
          size_t off = (((size_t)((batch * Tt + tt) * Cc + CBASE + c)) << 12)
                     + ((oh * PH + py) << 6) + ow * PW + px;
          O[off] = acc[mi][ni][r];
        }
      }
    }
  } else {
    const int nb = gz / KSPLIT;
    float* O = (float*)outPtr + ((size_t)ks * nb + batch) * oBatch;
#pragma unroll
    for (int mi = 0; mi < MI_; ++mi) {
      const int row0 = rowBase + wm * (MI_ * 16) + mi * 16 + lk * 4;
#pragma unroll
      for (int ni = 0; ni < NI_; ++ni) {
        const int col = colBase + wn * (NI_ * 16) + ni * 16 + lr;
#pragma unroll
        for (int r = 0; r < 4; ++r)
          O[(size_t)(row0 + r) * NP + col] = acc[mi][ni][r] * scale;
      }
    }
  }
}

// ---------------- row softmax over bf16 scores, in place ----------------
template<int NP>
__global__ __launch_bounds__(256) void softmax_rows(ushort_t* __restrict__ P) {
  constexpr int PER = NP / 256;
  constexpr int CH  = NP / 1024;
  ushort_t* row = P + (size_t)blockIdx.x * NP;
  const int tid = threadIdx.x;
  float v[PER];
  #pragma unroll
  for (int j = 0; j < CH; ++j) {
    short4v s = *(const short4v*)(row + j * 1024 + tid * 4);
    #pragma unroll
    for (int jj = 0; jj < 4; ++jj) v[4 * j + jj] = b2f((ushort_t)s[jj]);
  }
  float m = -1e30f;
  #pragma unroll
  for (int j = 0; j < PER; ++j) m = fmaxf(m, v[j]);
  #pragma unroll
  for (int o = 32; o >= 1; o >>= 1) m = fmaxf(m, __shfl_xor(m, o));
  __shared__ float redm[4];
  if ((tid & 63) == 0) redm[tid >> 6] = m;
  __syncthreads();
  m = fmaxf(fmaxf(redm[0], redm[1]), fmaxf(redm[2], redm[3]));
  float sum = 0.f;
  #pragma unroll
  for (int j = 0; j < PER; ++j) { v[j] = __expf(v[j] - m); sum += v[j]; }
  #pragma unroll
  for (int o = 32; o >= 1; o >>= 1) sum += __shfl_xor(sum, o);
  __shared__ float reds[4];
  if ((tid & 63) == 0) reds[tid >> 6] = sum;
  __syncthreads();
  sum = reds[0] + reds[1] + reds[2] + reds[3];
  const float inv = 1.0f / sum;
  #pragma unroll
  for (int j = 0; j < CH; ++j) {
    short4v o;
    #pragma unroll
    for (int jj = 0; jj < 4; ++jj) o[jj] = (short)f2b(v[4 * j + jj] * inv);
    *(short4v*)(row + j * 1024 + tid * 4) = o;
  }
}

// ---------------- combine 8 fp32 split-K partials + softmax -> bf16 P (patch 0, NP=1024) ----------------
__global__ __launch_bounds__(256) void softmax_combine_p0(const float* __restrict__ part,
                                                          ushort_t* __restrict__ P) {
  const int tid = threadIdx.x;
  const int b = blockIdx.x >> 10;          // batch
  const int m = blockIdx.x & 1023;         // row within batch
  float v[4] = {0.f, 0.f, 0.f, 0.f};
  #pragma unroll
  for (int ks = 0; ks < 8; ++ks) {
    const float* r = part + ((size_t)(ks * 2 + b) * 1024 + m) * 1024 + tid * 4;
    float4 a = *(const float4*)r;
    v[0] += a.x; v[1] += a.y; v[2] += a.z; v[3] += a.w;
  }
  float mx = fmaxf(fmaxf(v[0], v[1]), fmaxf(v[2], v[3]));
  #pragma unroll
  for (int o = 32; o >= 1; o >>= 1) mx = fmaxf(mx, __shfl_xor(mx, o));
  __shared__ float redm[4], reds[4];
  if ((tid & 63) == 0) redm[tid >> 6] = mx;
  __syncthreads();
  mx = fmaxf(fmaxf(redm[0], redm[1]), fmaxf(redm[2], redm[3]));
  float sum = 0.f;
  #pragma unroll
  for (int j = 0; j < 4; ++j) { v[j] = __expf(v[j] - mx); sum += v[j]; }
  #pragma unroll
  for (int o = 32; o >= 1; o >>= 1) sum += __shfl_xor(sum, o);
  if ((tid & 63) == 0) reds[tid >> 6] = sum;
  __syncthreads();
  sum = reds[0] + reds[1] + reds[2] + reds[3];
  const float inv = 1.0f / sum;
  short4v o4;
  #pragma unroll
  for (int j = 0; j < 4; ++j) o4[j] = (short)f2b(v[j] * inv);
  *(short4v*)(P + ((size_t)(b * 1024 + m)) * 1024 + tid * 4) = o4;
}

extern "C" void kernel_launch(void* const* d_in, const int* in_sizes, int n_in,
                              void* d_out, int out_size, void* d_ws, size_t ws_size,
                              hipStream_t stream) {
  const float* q = (const float*)d_in[0];
  const float* k = (const float*)d_in[1];
  const float* v = (const float*)d_in[2];
  ushort_t* wsA = (ushort_t*)d_ws;
  ushort_t* wsB = wsA + (size_t)33554432;          // 64 MiB in
  ushort_t* wsP = wsB + (size_t)33554432;          // 128 MiB in
  const size_t P1OFF = 16777216;                   // patch-1 offset within A/B regions (elems)
  const size_t PP1   = 2097152;                    // patch-1 offset within P region (elems)
  float* part = (float*)(wsP + PP1);               // QK-p0 split-K partials (64 MiB), overlaid on P-p1 region

  // tokenize Q, K
  tok_qk<8, 8, 0,   1024><<<8192,  256, 0, stream>>>(q, wsA);
  tok_qk<4, 4, 128, 4096><<<16384, 256, 0, stream>>>(q, wsA + P1OFF);
  tok_qk<8, 8, 0,   1024><<<8192,  256, 0, stream>>>(k, wsB);
  tok_qk<4, 4, 128, 4096><<<16384, 256, 0, stream>>>(k, wsB + P1OFF);

  // QK p0: 256^2 tile, split-K=8 -> fp32 partials [ks][b][1024][1024]; fused combine+softmax
  gemm_pipe<2, 8, 1024, 1, 1, 0><<<dim3(4, 4, 16), 512, 0, stream>>>(
      wsA, wsB, (size_t)1024 * 8192, (size_t)1024 * 8192, 8192, 32,
      part, (size_t)1048576, 0.011048543456039806f);
  softmax_combine_p0<<<2048, 256, 0, stream>>>(part, wsP);

  // QK p1: 256^2 tile (overwrites partial region AFTER combine consumed it)
  gemm_pipe<0, 1, 4096, 1, 1, 0><<<dim3(16, 16, 2), 512, 0, stream>>>(
      wsA + P1OFF, wsB + P1OFF, (size_t)4096 * 2048, (size_t)4096 * 2048, 2048, 64,
      wsP + PP1, (size_t)4096 * 4096, 0.022097086912079612f);
  softmax_rows<4096><<<8192, 256, 0, stream>>>(wsP + PP1);

  // tokenize V transposed into A region (Q tokens no longer needed)
  tok_vt<8, 8, 0,   1024><<<8192,  256, 0, stream>>>(v, wsA);
  tok_vt<4, 4, 128, 4096><<<16384, 256, 0, stream>>>(v, wsA + P1OFF);

  // O = P * V -> scatter fp32 into d_out
  gemm_pipe<1, 1, 0, 8, 8, 0><<<dim3(32, 4, 2), 512, 0, stream>>>(
      wsP, wsA, (size_t)1024 * 1024, (size_t)8192 * 1024, 1024, 32, d_out, 0, 1.0f);
  gemm_pipe<1, 1, 0, 4, 4, 128><<<dim3(8, 16, 2), 512, 0, stream>>>(
      wsP + PP1, wsA + P1OFF, (size_t)4096 * 4096, (size_t)2048 * 4096, 4096, 128, d_out, 0, 1.0f);
}

// Round 4
// 722.483 us; speedup vs baseline: 1.2458x; 1.0005x over previous
//
#include <hip/hip_runtime.h>
#include <hip/hip_bf16.h>
#include <stdint.h>

typedef unsigned short ushort_t;
typedef unsigned int uint_t;

typedef __bf16 bf16x8 __attribute__((ext_vector_type(8)));
typedef float f32x4 __attribute__((ext_vector_type(4)));
typedef short short4v __attribute__((ext_vector_type(4)));

typedef const __attribute__((address_space(1))) void gv_t;
typedef __attribute__((address_space(3))) void lv_t;

__device__ __forceinline__ ushort_t f2b(float f) {
  uint_t u = __builtin_bit_cast(uint_t, f);
  u += 0x7FFFu + ((u >> 16) & 1u);   // round-to-nearest-even
  return (ushort_t)(u >> 16);
}
__device__ __forceinline__ float b2f(ushort_t s) {
  return __builtin_bit_cast(float, (uint_t)s << 16);
}
constexpr int ilog2c(int x) { return x <= 1 ? 0 : 1 + ilog2c(x >> 1); }

constexpr int Tt = 16, Cc = 256, Hh = 64, Ww = 64, DKc = 128;

// ---------------- tokenize Q/K: (B*T,128,H,W) slice -> (b, n, d) bf16 row-major ----------------
template<int PH, int PW, int CBASE, int NP>
__global__ __launch_bounds__(256) void tok_qk(const float* __restrict__ src, ushort_t* __restrict__ dst) {
  constexpr int OHN = Hh / PH, OWN = Ww / PW, DP = DKc * PH * PW, OHW = OHN * OWN;
  const int id = blockIdx.x * 256 + threadIdx.x;
  const int py = id & (PH - 1);
  const int c  = (id >> ilog2c(PH)) & (DKc - 1);
  const int n  = (id >> (ilog2c(PH) + 7)) & (NP - 1);
  const int b  = id >> (ilog2c(PH) + 7 + ilog2c(NP));
  const int t  = n >> ilog2c(OHW);
  const int rem = n & (OHW - 1);
  const int oh = rem >> ilog2c(OWN);
  const int ow = rem & (OWN - 1);
  const float* s = src + (((size_t)((b * Tt + t) * Cc + CBASE + c)) << 12)
                       + ((oh * PH + py) << 6) + ow * PW;
  ushort_t* d = dst + (size_t)(b * NP + n) * DP + (c * PH + py) * PW;
  float4 f0 = *(const float4*)s;
  short4v o0; o0[0] = f2b(f0.x); o0[1] = f2b(f0.y); o0[2] = f2b(f0.z); o0[3] = f2b(f0.w);
  *(short4v*)d = o0;
  if constexpr (PW == 8) {
    float4 f1 = *(const float4*)(s + 4);
    short4v o1; o1[0] = f2b(f1.x); o1[1] = f2b(f1.y); o1[2] = f2b(f1.z); o1[3] = f2b(f1.w);
    *(short4v*)(d + 4) = o1;
  }
}

// ---------------- tokenize V transposed: -> (b, d, n) bf16 row-major ----------------
template<int PH, int PW, int CBASE, int NP>
__global__ __launch_bounds__(256) void tok_vt(const float* __restrict__ src, ushort_t* __restrict__ dst) {
  constexpr int OHN = Hh / PH, OWN = Ww / PW, DP = DKc * PH * PW;
  constexpr int CH = PW, NCH = OWN / CH;
  const int id  = blockIdx.x * 256 + threadIdx.x;
  const int owc = id & (NCH - 1);
  const int oh  = (id >> ilog2c(NCH)) & (OHN - 1);
  const int t   = (id >> (ilog2c(NCH) + ilog2c(OHN))) & (Tt - 1);
  const int dd  = (id >> (ilog2c(NCH) + ilog2c(OHN) + 4)) & (DP - 1);
  const int b   = id >> (ilog2c(NCH) + ilog2c(OHN) + 4 + ilog2c(DP));
  const int c   = dd >> ilog2c(PH * PW);
  const int py  = (dd >> ilog2c(PW)) & (PH - 1);
  const int px  = dd & (PW - 1);
  const float* s = src + (((size_t)((b * Tt + t) * Cc + CBASE + c)) << 12)
                       + ((oh * PH + py) << 6) + px;
  const int n0 = (t * OHN + oh) * OWN + owc * CH;
  ushort_t* d = dst + (size_t)(b * DP + dd) * NP + n0;
  short4v o;
  #pragma unroll
  for (int j = 0; j < 4; ++j) o[j] = f2b(s[(owc * CH + j) * PW]);
  *(short4v*)d = o;
  if constexpr (CH == 8) {
    short4v o2;
    #pragma unroll
    for (int j = 0; j < 4; ++j) o2[j] = f2b(s[(owc * CH + 4 + j) * PW]);
    *(short4v*)(d + 4) = o2;
  }
}

__device__ __forceinline__ void waitvm6() { asm volatile("s_waitcnt vmcnt(6)" ::: "memory"); }
__device__ __forceinline__ void waitvm0() { asm volatile("s_waitcnt vmcnt(0)" ::: "memory"); }
__device__ __forceinline__ void waitlg0() { asm volatile("s_waitcnt lgkmcnt(0)" ::: "memory"); }

// ---------------- 256x256/BK=64, 4-phase double-buffered NT GEMM (m201 schedule) ----------------
// C(MxN) = A(MxK) * B(NxK)^T, bf16 in, fp32 acc.
// EPI 0: bf16 scores*scale -> P (row-major, ld=NP)
// EPI 1: fp32 scatter to d_out via from_tokens mapping
// EPI 2: fp32 linear partial (split-K), layout [ks][batch][M][NP]
template<int EPI, int KSPLIT, int NP, int PH, int PW, int CBASE>
__global__ __launch_bounds__(512, 2)
void gemm_pipe(const ushort_t* __restrict__ A, const ushort_t* __restrict__ B,
               size_t aBatch, size_t bBatch, int ldk, int nt,
               void* __restrict__ outPtr, size_t oBatch, float scale) {
  constexpr int MI_ = 8, NI_ = 4;
  __shared__ __align__(16) ushort_t As[2 * 256 * 64];   // [buf][256 rows][64 K] swizzled
  __shared__ __align__(16) ushort_t Bs[2 * 256 * 64];

  const int tid = threadIdx.x;
  const int w = tid >> 6, l = tid & 63;
  const int wm = w >> 2, wn = w & 3;
  const int lr = l & 15, lk = l >> 4;
  const int srow8 = tid >> 3;                 // staging row within 64-row round
  const int gcolS = (((tid & 7) ^ (srow8 & 7)) << 3);   // pre-swizzled global col (bf16)
  const int sw0 = ((lk ^ (lr & 7)) << 4);     // swizzled byte slot, ks=0
  const int sw1 = sw0 ^ 64;                   // ks=1

  // XCD-aware swizzle of linear block id (grid size always a multiple of 8)
  const int gx = gridDim.x, gy = gridDim.y, gz = gridDim.z;
  int id = (blockIdx.z * gy + blockIdx.y) * gx + blockIdx.x;
  const int cpx = (gx * gy * gz) >> 3;
  id = (id & 7) * cpx + (id >> 3);
  const int bx = id % gx;
  const int rst = id / gx;
  const int by = rst % gy;
  const int bz = rst / gy;

  int batch = bz, ks = 0;
  if constexpr (KSPLIT > 1) { batch = bz / KSPLIT; ks = bz - batch * KSPLIT; }

  const int rowBase = by * 256, colBase = bx * 256;
  const ushort_t* Ab = A + (size_t)batch * aBatch + (size_t)ks * nt * 64;
  const ushort_t* Bb = B + (size_t)batch * bBatch + (size_t)ks * nt * 64;

  f32x4 acc[MI_][NI_] = {};

  // stage one 64-row round (r in 0..3) of a K-tile kt into buffer buf
  auto stgA = [&](int buf, int r, int kt) {
    const int rr = r * 64 + srow8;
    const ushort_t* g = Ab + (size_t)(rowBase + rr) * ldk + kt * 64 + gcolS;
    __builtin_amdgcn_global_load_lds((gv_t*)g, (lv_t*)((char*)As + buf * 32768 + r * 8192 + w * 1024), 16, 0, 0);
  };
  auto stgB = [&](int buf, int r, int kt) {
    const int rr = r * 64 + srow8;
    const ushort_t* g = Bb + (size_t)(colBase + rr) * ldk + kt * 64 + gcolS;
    __builtin_amdgcn_global_load_lds((gv_t*)g, (lv_t*)((char*)Bs + buf * 32768 + r * 8192 + w * 1024), 16, 0, 0);
  };

  auto rdA = [&](int buf, int mh, int ksx, bf16x8* a) {
    const char* base = (const char*)As + buf * 32768 + (wm * 128 + mh * 64 + lr) * 128 + (ksx ? sw1 : sw0);
#pragma unroll
    for (int mi = 0; mi < 4; ++mi) a[mi] = *(const bf16x8*)(base + mi * 2048);
  };
  auto rdB = [&](int buf, int ksx, bf16x8* b) {
    const char* base = (const char*)Bs + buf * 32768 + (wn * 64 + lr) * 128 + (ksx ? sw1 : sw0);
#pragma unroll
    for (int ni = 0; ni < 4; ++ni) b[ni] = *(const bf16x8*)(base + ni * 2048);
  };
  auto mm = [&](const bf16x8* a, const bf16x8* b, int mh) {
    __builtin_amdgcn_s_setprio(1);
#pragma unroll
    for (int mi = 0; mi < 4; ++mi)
#pragma unroll
      for (int ni = 0; ni < 4; ++ni)
        acc[mh * 4 + mi][ni] = __builtin_amdgcn_mfma_f32_16x16x32_bf16(a[mi], b[ni], acc[mh * 4 + mi][ni], 0, 0, 0);
    __builtin_amdgcn_s_setprio(0);
  };

  // prologue: tile0 full (8 loads), tile1 partial (B all + A rounds 0,2 = 6 loads)
  stgA(0, 0, 0); stgA(0, 1, 0); stgA(0, 2, 0); stgA(0, 3, 0);
  stgB(0, 0, 0); stgB(0, 1, 0); stgB(0, 2, 0); stgB(0, 3, 0);
  if (nt > 1) {
    stgB(1, 0, 1); stgB(1, 1, 1); stgB(1, 2, 1); stgB(1, 3, 1);
    stgA(1, 0, 1); stgA(1, 2, 1);
    waitvm6();
  } else {
    waitvm0();
  }
  __builtin_amdgcn_s_barrier();

  for (int t = 0; t < nt; ++t) {
    const int c = t & 1;
    bf16x8 a[4], b0[4], b1[4];
    // ---- p0: (mh0, ks0); finish tile t+1 staging (A rounds 1,3) ----
    rdA(c, 0, 0, a);
    rdB(c, 0, b0);
    if (t + 1 < nt) { stgA(c ^ 1, 1, t + 1); stgA(c ^ 1, 3, t + 1); }
    __builtin_amdgcn_s_barrier();
    waitlg0();
    __builtin_amdgcn_sched_barrier(0);
    mm(a, b0, 0);
    __builtin_amdgcn_s_barrier();
    // ---- p1: (mh0, ks1) ----
    rdA(c, 0, 1, a);
    rdB(c, 1, b1);
    __builtin_amdgcn_s_barrier();
    waitlg0();
    __builtin_amdgcn_sched_barrier(0);
    mm(a, b1, 0);
    __builtin_amdgcn_s_barrier();
    // ---- p2: (mh1, ks0); stage tile t+2 (B all + A rounds 0,2) into this buffer ----
    rdA(c, 1, 0, a);
    if (t + 2 < nt) {
      stgB(c, 0, t + 2); stgB(c, 1, t + 2); stgB(c, 2, t + 2); stgB(c, 3, t + 2);
      stgA(c, 0, t + 2); stgA(c, 2, t + 2);
    }
    __builtin_amdgcn_s_barrier();
    waitlg0();
    __builtin_amdgcn_sched_barrier(0);
    mm(a, b0, 1);
    __builtin_amdgcn_s_barrier();
    // ---- p3: (mh1, ks1); counted drain: tile t+1 landed, t+2's 6 stay in flight ----
    rdA(c, 1, 1, a);
    __builtin_amdgcn_s_barrier();
    waitlg0();
    __builtin_amdgcn_sched_barrier(0);
    mm(a, b1, 1);
    if (t + 2 < nt) waitvm6();
    else if (t + 1 < nt) waitvm0();
    __builtin_amdgcn_s_barrier();
  }

  if constexpr (EPI == 0) {
    ushort_t* P = (ushort_t*)outPtr + (size_t)batch * oBatch;
#pragma unroll
    for (int mi = 0; mi < MI_; ++mi) {
      const int row0 = rowBase + wm * 128 + mi * 16 + lk * 4;
#pragma unroll
      for (int ni = 0; ni < NI_; ++ni) {
        const int col = colBase + wn * 64 + ni * 16 + lr;
#pragma unroll
        for (int r = 0; r < 4; ++r)
          P[(size_t)(row0 + r) * NP + col] = f2b(acc[mi][ni][r] * scale);
      }
    }
  } else if constexpr (EPI == 1) {
    float* O = (float*)outPtr;
    constexpr int OWN = Ww / PW;
    constexpr int OHW = (Hh / PH) * OWN;
    constexpr int PHPW = PH * PW;
#pragma unroll
    for (int mi = 0; mi < MI_; ++mi) {
#pragma unroll
      for (int ni = 0; ni < NI_; ++ni) {
        const int d = colBase + wn * 64 + ni * 16 + lr;
        const int c   = d >> ilog2c(PHPW);
        const int pyx = d & (PHPW - 1);
        const int py  = pyx >> ilog2c(PW);
        const int px  = pyx & (PW - 1);
#pragma unroll
        for (int r = 0; r < 4; ++r) {
          const int qq = rowBase + wm * 128 + mi * 16 + lk * 4 + r;
          const int tt = qq >> ilog2c(OHW);
          const int rm = qq & (OHW - 1);
          const int oh = rm >> ilog2c(OWN);
          const int ow = rm & (OWN - 1);
          size_t off = (((size_t)((batch * Tt + tt) * Cc + CBASE + c)) << 12)
                     + ((oh * PH + py) << 6) + ow * PW + px;
          O[off] = acc[mi][ni][r];
        }
      }
    }
  } else {
    const int nb = gz / KSPLIT;
    float* O = (float*)outPtr + ((size_t)ks * nb + batch) * oBatch;
#pragma unroll
    for (int mi = 0; mi < MI_; ++mi) {
      const int row0 = rowBase + wm * 128 + mi * 16 + lk * 4;
#pragma unroll
      for (int ni = 0; ni < NI_; ++ni) {
        const int col = colBase + wn * 64 + ni * 16 + lr;
#pragma unroll
        for (int r = 0; r < 4; ++r)
          O[(size_t)(row0 + r) * NP + col] = acc[mi][ni][r] * scale;
      }
    }
  }
}

// ---------------- row softmax over bf16 scores, in place ----------------
template<int NP>
__global__ __launch_bounds__(256) void softmax_rows(ushort_t* __restrict__ P) {
  constexpr int PER = NP / 256;
  constexpr int CH  = NP / 1024;
  ushort_t* row = P + (size_t)blockIdx.x * NP;
  const int tid = threadIdx.x;
  float v[PER];
  #pragma unroll
  for (int j = 0; j < CH; ++j) {
    short4v s = *(const short4v*)(row + j * 1024 + tid * 4);
    #pragma unroll
    for (int jj = 0; jj < 4; ++jj) v[4 * j + jj] = b2f((ushort_t)s[jj]);
  }
  float m = -1e30f;
  #pragma unroll
  for (int j = 0; j < PER; ++j) m = fmaxf(m, v[j]);
  #pragma unroll
  for (int o = 32; o >= 1; o >>= 1) m = fmaxf(m, __shfl_xor(m, o));
  __shared__ float redm[4];
  if ((tid & 63) == 0) redm[tid >> 6] = m;
  __syncthreads();
  m = fmaxf(fmaxf(redm[0], redm[1]), fmaxf(redm[2], redm[3]));
  float sum = 0.f;
  #pragma unroll
  for (int j = 0; j < PER; ++j) { v[j] = __expf(v[j] - m); sum += v[j]; }
  #pragma unroll
  for (int o = 32; o >= 1; o >>= 1) sum += __shfl_xor(sum, o);
  __shared__ float reds[4];
  if ((tid & 63) == 0) reds[tid >> 6] = sum;
  __syncthreads();
  sum = reds[0] + reds[1] + reds[2] + reds[3];
  const float inv = 1.0f / sum;
  #pragma unroll
  for (int j = 0; j < CH; ++j) {
    short4v o;
    #pragma unroll
    for (int jj = 0; jj < 4; ++jj) o[jj] = (short)f2b(v[4 * j + jj] * inv);
    *(short4v*)(row + j * 1024 + tid * 4) = o;
  }
}

// ---------------- combine 8 fp32 split-K partials + softmax -> bf16 P (patch 0, NP=1024) ----------------
__global__ __launch_bounds__(256) void softmax_combine_p0(const float* __restrict__ part,
                                                          ushort_t* __restrict__ P) {
  const int tid = threadIdx.x;
  const int b = blockIdx.x >> 10;          // batch
  const int m = blockIdx.x & 1023;         // row within batch
  float v[4] = {0.f, 0.f, 0.f, 0.f};
  #pragma unroll
  for (int ks = 0; ks < 8; ++ks) {
    const float* r = part + ((size_t)(ks * 2 + b) * 1024 + m) * 1024 + tid * 4;
    float4 a = *(const float4*)r;
    v[0] += a.x; v[1] += a.y; v[2] += a.z; v[3] += a.w;
  }
  float mx = fmaxf(fmaxf(v[0], v[1]), fmaxf(v[2], v[3]));
  #pragma unroll
  for (int o = 32; o >= 1; o >>= 1) mx = fmaxf(mx, __shfl_xor(mx, o));
  __shared__ float redm[4], reds[4];
  if ((tid & 63) == 0) redm[tid >> 6] = mx;
  __syncthreads();
  mx = fmaxf(fmaxf(redm[0], redm[1]), fmaxf(redm[2], redm[3]));
  float sum = 0.f;
  #pragma unroll
  for (int j = 0; j < 4; ++j) { v[j] = __expf(v[j] - mx); sum += v[j]; }
  #pragma unroll
  for (int o = 32; o >= 1; o >>= 1) sum += __shfl_xor(sum, o);
  if ((tid & 63) == 0) reds[tid >> 6] = sum;
  __syncthreads();
  sum = reds[0] + reds[1] + reds[2] + reds[3];
  const float inv = 1.0f / sum;
  short4v o4;
  #pragma unroll
  for (int j = 0; j < 4; ++j) o4[j] = (short)f2b(v[j] * inv);
  *(short4v*)(P + ((size_t)(b * 1024 + m)) * 1024 + tid * 4) = o4;
}

extern "C" void kernel_launch(void* const* d_in, const int* in_sizes, int n_in,
                              void* d_out, int out_size, void* d_ws, size_t ws_size,
                              hipStream_t stream) {
  const float* q = (const float*)d_in[0];
  const float* k = (const float*)d_in[1];
  const float* v = (const float*)d_in[2];
  ushort_t* wsA = (ushort_t*)d_ws;
  ushort_t* wsB = wsA + (size_t)33554432;          // 64 MiB in
  ushort_t* wsP = wsB + (size_t)33554432;          // 128 MiB in
  const size_t P1OFF = 16777216;                   // patch-1 offset within A/B regions (elems)
  const size_t PP1   = 2097152;                    // patch-1 offset within P region (elems)
  float* part = (float*)(wsP + PP1);               // QK-p0 split-K partials (64 MiB), overlaid on P-p1 region

  // tokenize Q, K
  tok_qk<8, 8, 0,   1024><<<8192,  256, 0, stream>>>(q, wsA);
  tok_qk<4, 4, 128, 4096><<<16384, 256, 0, stream>>>(q, wsA + P1OFF);
  tok_qk<8, 8, 0,   1024><<<8192,  256, 0, stream>>>(k, wsB);
  tok_qk<4, 4, 128, 4096><<<16384, 256, 0, stream>>>(k, wsB + P1OFF);

  // QK p0: split-K=8 -> fp32 partials [ks][b][1024][1024]; fused combine+softmax
  gemm_pipe<2, 8, 1024, 1, 1, 0><<<dim3(4, 4, 16), 512, 0, stream>>>(
      wsA, wsB, (size_t)1024 * 8192, (size_t)1024 * 8192, 8192, 16,
      part, (size_t)1048576, 0.011048543456039806f);
  softmax_combine_p0<<<2048, 256, 0, stream>>>(part, wsP);

  // QK p1 (overwrites partial region AFTER combine consumed it)
  gemm_pipe<0, 1, 4096, 1, 1, 0><<<dim3(16, 16, 2), 512, 0, stream>>>(
      wsA + P1OFF, wsB + P1OFF, (size_t)4096 * 2048, (size_t)4096 * 2048, 2048, 32,
      wsP + PP1, (size_t)4096 * 4096, 0.022097086912079612f);
  softmax_rows<4096><<<8192, 256, 0, stream>>>(wsP + PP1);

  // tokenize V transposed into A region (Q tokens no longer needed)
  tok_vt<8, 8, 0,   1024><<<8192,  256, 0, stream>>>(v, wsA);
  tok_vt<4, 4, 128, 4096><<<16384, 256, 0, stream>>>(v, wsA + P1OFF);

  // O = P * V -> scatter fp32 into d_out
  gemm_pipe<1, 1, 0, 8, 8, 0><<<dim3(32, 4, 2), 512, 0, stream>>>(
      wsP, wsA, (size_t)1024 * 1024, (size_t)8192 * 1024, 1024, 16, d_out, 0, 1.0f);
  gemm_pipe<1, 1, 0, 4, 4, 128><<<dim3(8, 16, 2), 512, 0, stream>>>(
      wsP + PP1, wsA + P1OFF, (size_t)4096 * 4096, (size_t)2048 * 4096, 4096, 64, d_out, 0, 1.0f);
}

// Round 5
// 652.330 us; speedup vs baseline: 1.3798x; 1.1075x over previous
//
#include <hip/hip_runtime.h>
#include <hip/hip_bf16.h>
#include <stdint.h>

typedef unsigned short ushort_t;
typedef unsigned int uint_t;

typedef __bf16 bf16x8 __attribute__((ext_vector_type(8)));
typedef float f32x4 __attribute__((ext_vector_type(4)));
typedef short short4v __attribute__((ext_vector_type(4)));

typedef const __attribute__((address_space(1))) void gv_t;
typedef __attribute__((address_space(3))) void lv_t;

__device__ __forceinline__ ushort_t f2b(float f) {
  uint_t u = __builtin_bit_cast(uint_t, f);
  u += 0x7FFFu + ((u >> 16) & 1u);   // round-to-nearest-even
  return (ushort_t)(u >> 16);
}
__device__ __forceinline__ float b2f(ushort_t s) {
  return __builtin_bit_cast(float, (uint_t)s << 16);
}
constexpr int ilog2c(int x) { return x <= 1 ? 0 : 1 + ilog2c(x >> 1); }

constexpr int Tt = 16, Cc = 256, Hh = 64, Ww = 64, DKc = 128;

// ---------------- tokenize Q/K: (B*T,128,H,W) slice -> (b, n, d) bf16 row-major ----------------
template<int PH, int PW, int CBASE, int NP>
__global__ __launch_bounds__(256) void tok_qk(const float* __restrict__ src, ushort_t* __restrict__ dst) {
  constexpr int OHN = Hh / PH, OWN = Ww / PW, DP = DKc * PH * PW, OHW = OHN * OWN;
  const int id = blockIdx.x * 256 + threadIdx.x;
  const int py = id & (PH - 1);
  const int c  = (id >> ilog2c(PH)) & (DKc - 1);
  const int n  = (id >> (ilog2c(PH) + 7)) & (NP - 1);
  const int b  = id >> (ilog2c(PH) + 7 + ilog2c(NP));
  const int t  = n >> ilog2c(OHW);
  const int rem = n & (OHW - 1);
  const int oh = rem >> ilog2c(OWN);
  const int ow = rem & (OWN - 1);
  const float* s = src + (((size_t)((b * Tt + t) * Cc + CBASE + c)) << 12)
                       + ((oh * PH + py) << 6) + ow * PW;
  ushort_t* d = dst + (size_t)(b * NP + n) * DP + (c * PH + py) * PW;
  float4 f0 = *(const float4*)s;
  short4v o0; o0[0] = f2b(f0.x); o0[1] = f2b(f0.y); o0[2] = f2b(f0.z); o0[3] = f2b(f0.w);
  *(short4v*)d = o0;
  if constexpr (PW == 8) {
    float4 f1 = *(const float4*)(s + 4);
    short4v o1; o1[0] = f2b(f1.x); o1[1] = f2b(f1.y); o1[2] = f2b(f1.z); o1[3] = f2b(f1.w);
    *(short4v*)(d + 4) = o1;
  }
}

// ---------------- tokenize V transposed: -> (b, d, n) bf16 row-major ----------------
template<int PH, int PW, int CBASE, int NP>
__global__ __launch_bounds__(256) void tok_vt(const float* __restrict__ src, ushort_t* __restrict__ dst) {
  constexpr int OHN = Hh / PH, OWN = Ww / PW, DP = DKc * PH * PW;
  constexpr int CH = PW, NCH = OWN / CH;
  const int id  = blockIdx.x * 256 + threadIdx.x;
  const int owc = id & (NCH - 1);
  const int oh  = (id >> ilog2c(NCH)) & (OHN - 1);
  const int t   = (id >> (ilog2c(NCH) + ilog2c(OHN))) & (Tt - 1);
  const int dd  = (id >> (ilog2c(NCH) + ilog2c(OHN) + 4)) & (DP - 1);
  const int b   = id >> (ilog2c(NCH) + ilog2c(OHN) + 4 + ilog2c(DP));
  const int c   = dd >> ilog2c(PH * PW);
  const int py  = (dd >> ilog2c(PW)) & (PH - 1);
  const int px  = dd & (PW - 1);
  const float* s = src + (((size_t)((b * Tt + t) * Cc + CBASE + c)) << 12)
                       + ((oh * PH + py) << 6) + px;
  const int n0 = (t * OHN + oh) * OWN + owc * CH;
  ushort_t* d = dst + (size_t)(b * DP + dd) * NP + n0;
  short4v o;
  #pragma unroll
  for (int j = 0; j < 4; ++j) o[j] = f2b(s[(owc * CH + j) * PW]);
  *(short4v*)d = o;
  if constexpr (CH == 8) {
    short4v o2;
    #pragma unroll
    for (int j = 0; j < 4; ++j) o2[j] = f2b(s[(owc * CH + 4 + j) * PW]);
    *(short4v*)(d + 4) = o2;
  }
}

#define SB0() __builtin_amdgcn_sched_barrier(0)
__device__ __forceinline__ void waitvm8() { asm volatile("s_waitcnt vmcnt(8)" ::: "memory"); }
__device__ __forceinline__ void waitvm6() { asm volatile("s_waitcnt vmcnt(6)" ::: "memory"); }
__device__ __forceinline__ void waitvm0() { asm volatile("s_waitcnt vmcnt(0)" ::: "memory"); }

// ---- 256x256/BK=64 double-buffered NT GEMM, 4 quadrant-phases/K-tile, read-ahead frags ----
// C(MxN) = A(MxK) * B(NxK)^T, bf16 in, fp32 acc.
// EPI 0: bf16 scores*scale -> P ; EPI 1: fp32 from_tokens scatter ; EPI 2: fp32 split-K partial
template<int EPI, int KSPLIT, int NP, int PH, int PW, int CBASE>
__global__ __launch_bounds__(512, 2)
void gemm_pipe(const ushort_t* __restrict__ A, const ushort_t* __restrict__ B,
               size_t aBatch, size_t bBatch, int ldk, int nt,
               void* __restrict__ outPtr, size_t oBatch, float scale) {
  __shared__ __align__(16) ushort_t As[2 * 256 * 64];
  __shared__ __align__(16) ushort_t Bs[2 * 256 * 64];

  const int tid = threadIdx.x;
  const int w = tid >> 6, l = tid & 63;
  const int wm = w >> 2, wn = w & 3;
  const int lr = l & 15, lk = l >> 4;
  const int srow8 = tid >> 3;                            // staging row within 64-row round
  const int gcolS = (((tid & 7) ^ (srow8 & 7)) << 3);    // pre-swizzled global col (bf16)
  const int sw0 = ((lk ^ (lr & 7)) << 4);                // swizzled byte slot, ks=0
  const int sw1 = sw0 ^ 64;                              // ks=1

  // XCD-aware bijective swizzle (grid always a multiple of 8)
  const int gx = gridDim.x, gy = gridDim.y, gz = gridDim.z;
  int id = (blockIdx.z * gy + blockIdx.y) * gx + blockIdx.x;
  const int cpx = (gx * gy * gz) >> 3;
  id = (id & 7) * cpx + (id >> 3);
  const int bx = id % gx;
  const int rst = id / gx;
  const int by = rst % gy;
  const int bz = rst / gy;

  int batch = bz, ks = 0;
  if constexpr (KSPLIT > 1) { batch = bz / KSPLIT; ks = bz - batch * KSPLIT; }

  const int rowBase = by * 256, colBase = bx * 256;
  const ushort_t* Ab = A + (size_t)batch * aBatch + (size_t)ks * nt * 64;
  const ushort_t* Bb = B + (size_t)batch * bBatch + (size_t)ks * nt * 64;

  f32x4 acc[8][4] = {};
  bf16x8 A0[8], A1[8], B0[4], B1[4];   // frag regs: [mi*2+ks] / [ni*2+ks]

  auto stgA = [&](int buf, int r, int kt) {
    const int rr = r * 64 + srow8;
    const ushort_t* g = Ab + (size_t)(rowBase + rr) * ldk + kt * 64 + gcolS;
    __builtin_amdgcn_global_load_lds((gv_t*)g, (lv_t*)((char*)As + buf * 32768 + r * 8192 + w * 1024), 16, 0, 0);
  };
  auto stgB = [&](int buf, int r, int kt) {
    const int rr = r * 64 + srow8;
    const ushort_t* g = Bb + (size_t)(colBase + rr) * ldk + kt * 64 + gcolS;
    __builtin_amdgcn_global_load_lds((gv_t*)g, (lv_t*)((char*)Bs + buf * 32768 + r * 8192 + w * 1024), 16, 0, 0);
  };

  auto rdA_ = [&](int buf, int mh, bf16x8* dst) {
    const char* b0p = (const char*)As + buf * 32768 + (wm * 128 + mh * 64 + lr) * 128;
#pragma unroll
    for (int mi = 0; mi < 4; ++mi) {
      dst[mi * 2 + 0] = *(const bf16x8*)(b0p + mi * 2048 + sw0);
      dst[mi * 2 + 1] = *(const bf16x8*)(b0p + mi * 2048 + sw1);
    }
  };
  auto rdB_ = [&](int buf, int nh, bf16x8* dst) {
    const char* b0p = (const char*)Bs + buf * 32768 + (wn * 64 + nh * 32 + lr) * 128;
#pragma unroll
    for (int ni = 0; ni < 2; ++ni) {
      dst[ni * 2 + 0] = *(const bf16x8*)(b0p + ni * 2048 + sw0);
      dst[ni * 2 + 1] = *(const bf16x8*)(b0p + ni * 2048 + sw1);
    }
  };
  auto mmq = [&](const bf16x8* a, const bf16x8* b, int mh, int nh) {
    __builtin_amdgcn_s_setprio(1);
#pragma unroll
    for (int mi = 0; mi < 4; ++mi)
#pragma unroll
      for (int ni = 0; ni < 2; ++ni) {
        f32x4& cc = acc[mh * 4 + mi][nh * 2 + ni];
        cc = __builtin_amdgcn_mfma_f32_16x16x32_bf16(a[mi * 2 + 0], b[ni * 2 + 0], cc, 0, 0, 0);
        cc = __builtin_amdgcn_mfma_f32_16x16x32_bf16(a[mi * 2 + 1], b[ni * 2 + 1], cc, 0, 0, 0);
      }
    __builtin_amdgcn_s_setprio(0);
  };

  // prologue: tile0 full (8 loads) + tile1 full (8 loads); drain tile0 only
  stgA(0, 0, 0); stgA(0, 1, 0); stgA(0, 2, 0); stgA(0, 3, 0);
  stgB(0, 0, 0); stgB(0, 1, 0); stgB(0, 2, 0); stgB(0, 3, 0);
  stgA(1, 0, 1); stgA(1, 2, 1);
  stgB(1, 0, 1); stgB(1, 1, 1); stgB(1, 2, 1); stgB(1, 3, 1);
  stgA(1, 1, 1); stgA(1, 3, 1);
  waitvm8();
  __builtin_amdgcn_s_barrier();
  rdA_(0, 0, A0);
  rdB_(0, 0, B0);

  for (int t = 0; t < nt; ++t) {
    const int c = t & 1;
    // ---- P0: MFMA (mh0,nh0); read-ahead B1 ----
    rdB_(c, 1, B1);
    SB0();
    __builtin_amdgcn_s_barrier();
    mmq(A0, B0, 0, 0);
    SB0();
    __builtin_amdgcn_s_barrier();
    // ---- P1: MFMA (mh0,nh1); read-ahead A1; stage t+2 A rounds 0,2 ----
    rdA_(c, 1, A1);
    if (t + 2 < nt) { stgA(c, 0, t + 2); stgA(c, 2, t + 2); }
    SB0();
    __builtin_amdgcn_s_barrier();
    mmq(A0, B1, 0, 1);
    SB0();
    __builtin_amdgcn_s_barrier();
    // ---- P2: MFMA (mh1,nh0); stage t+2 B all; counted vmcnt guarantees t+1 landed ----
    if (t + 2 < nt) {
      stgB(c, 0, t + 2); stgB(c, 1, t + 2); stgB(c, 2, t + 2); stgB(c, 3, t + 2);
      waitvm6();
    } else if (t + 1 < nt) {
      waitvm0();
    }
    SB0();
    __builtin_amdgcn_s_barrier();
    mmq(A1, B0, 1, 0);
    SB0();
    __builtin_amdgcn_s_barrier();
    // ---- P3: MFMA (mh1,nh1); read-ahead next tile's A0,B0; stage t+2 A rounds 1,3 ----
    if (t + 1 < nt) { rdA_(c ^ 1, 0, A0); rdB_(c ^ 1, 0, B0); }
    if (t + 2 < nt) { stgA(c, 1, t + 2); stgA(c, 3, t + 2); }
    SB0();
    __builtin_amdgcn_s_barrier();
    mmq(A1, B1, 1, 1);
    SB0();
    __builtin_amdgcn_s_barrier();
  }

  if constexpr (EPI == 0) {
    ushort_t* P = (ushort_t*)outPtr + (size_t)batch * oBatch;
#pragma unroll
    for (int mi = 0; mi < 8; ++mi) {
      const int row0 = rowBase + wm * 128 + mi * 16 + lk * 4;
#pragma unroll
      for (int ni = 0; ni < 4; ++ni) {
        const int col = colBase + wn * 64 + ni * 16 + lr;
#pragma unroll
        for (int r = 0; r < 4; ++r)
          P[(size_t)(row0 + r) * NP + col] = f2b(acc[mi][ni][r] * scale);
      }
    }
  } else if constexpr (EPI == 1) {
    float* O = (float*)outPtr;
    constexpr int OWN = Ww / PW;
    constexpr int OHW = (Hh / PH) * OWN;
    constexpr int PHPW = PH * PW;
#pragma unroll
    for (int mi = 0; mi < 8; ++mi) {
#pragma unroll
      for (int ni = 0; ni < 4; ++ni) {
        const int d = colBase + wn * 64 + ni * 16 + lr;
        const int c   = d >> ilog2c(PHPW);
        const int pyx = d & (PHPW - 1);
        const int py  = pyx >> ilog2c(PW);
        const int px  = pyx & (PW - 1);
#pragma unroll
        for (int r = 0; r < 4; ++r) {
          const int qq = rowBase + wm * 128 + mi * 16 + lk * 4 + r;
          const int tt = qq >> ilog2c(OHW);
          const int rm = qq & (OHW - 1);
          const int oh = rm >> ilog2c(OWN);
          const int ow = rm & (OWN - 1);
          size_t off = (((size_t)((batch * Tt + tt) * Cc + CBASE + c)) << 12)
                     + ((oh * PH + py) << 6) + ow * PW + px;
          O[off] = acc[mi][ni][r];
        }
      }
    }
  } else {
    const int nb = gz / KSPLIT;
    float* O = (float*)outPtr + ((size_t)ks * nb + batch) * oBatch;
#pragma unroll
    for (int mi = 0; mi < 8; ++mi) {
      const int row0 = rowBase + wm * 128 + mi * 16 + lk * 4;
#pragma unroll
      for (int ni = 0; ni < 4; ++ni) {
        const int col = colBase + wn * 64 + ni * 16 + lr;
#pragma unroll
        for (int r = 0; r < 4; ++r)
          O[(size_t)(row0 + r) * NP + col] = acc[mi][ni][r] * scale;
      }
    }
  }
}

// ---------------- row softmax over bf16 scores, in place ----------------
template<int NP>
__global__ __launch_bounds__(256) void softmax_rows(ushort_t* __restrict__ P) {
  constexpr int PER = NP / 256;
  constexpr int CH  = NP / 1024;
  ushort_t* row = P + (size_t)blockIdx.x * NP;
  const int tid = threadIdx.x;
  float v[PER];
  #pragma unroll
  for (int j = 0; j < CH; ++j) {
    short4v s = *(const short4v*)(row + j * 1024 + tid * 4);
    #pragma unroll
    for (int jj = 0; jj < 4; ++jj) v[4 * j + jj] = b2f((ushort_t)s[jj]);
  }
  float m = -1e30f;
  #pragma unroll
  for (int j = 0; j < PER; ++j) m = fmaxf(m, v[j]);
  #pragma unroll
  for (int o = 32; o >= 1; o >>= 1) m = fmaxf(m, __shfl_xor(m, o));
  __shared__ float redm[4];
  if ((tid & 63) == 0) redm[tid >> 6] = m;
  __syncthreads();
  m = fmaxf(fmaxf(redm[0], redm[1]), fmaxf(redm[2], redm[3]));
  float sum = 0.f;
  #pragma unroll
  for (int j = 0; j < PER; ++j) { v[j] = __expf(v[j] - m); sum += v[j]; }
  #pragma unroll
  for (int o = 32; o >= 1; o >>= 1) sum += __shfl_xor(sum, o);
  __shared__ float reds[4];
  if ((tid & 63) == 0) reds[tid >> 6] = sum;
  __syncthreads();
  sum = reds[0] + reds[1] + reds[2] + reds[3];
  const float inv = 1.0f / sum;
  #pragma unroll
  for (int j = 0; j < CH; ++j) {
    short4v o;
    #pragma unroll
    for (int jj = 0; jj < 4; ++jj) o[jj] = (short)f2b(v[4 * j + jj] * inv);
    *(short4v*)(row + j * 1024 + tid * 4) = o;
  }
}

// ---------------- combine 8 fp32 split-K partials + softmax -> bf16 P (patch 0, NP=1024) ----------------
__global__ __launch_bounds__(256) void softmax_combine_p0(const float* __restrict__ part,
                                                          ushort_t* __restrict__ P) {
  const int tid = threadIdx.x;
  const int b = blockIdx.x >> 10;          // batch
  const int m = blockIdx.x & 1023;         // row within batch
  float v[4] = {0.f, 0.f, 0.f, 0.f};
  #pragma unroll
  for (int ks = 0; ks < 8; ++ks) {
    const float* r = part + ((size_t)(ks * 2 + b) * 1024 + m) * 1024 + tid * 4;
    float4 a = *(const float4*)r;
    v[0] += a.x; v[1] += a.y; v[2] += a.z; v[3] += a.w;
  }
  float mx = fmaxf(fmaxf(v[0], v[1]), fmaxf(v[2], v[3]));
  #pragma unroll
  for (int o = 32; o >= 1; o >>= 1) mx = fmaxf(mx, __shfl_xor(mx, o));
  __shared__ float redm[4], reds[4];
  if ((tid & 63) == 0) redm[tid >> 6] = mx;
  __syncthreads();
  mx = fmaxf(fmaxf(redm[0], redm[1]), fmaxf(redm[2], redm[3]));
  float sum = 0.f;
  #pragma unroll
  for (int j = 0; j < 4; ++j) { v[j] = __expf(v[j] - mx); sum += v[j]; }
  #pragma unroll
  for (int o = 32; o >= 1; o >>= 1) sum += __shfl_xor(sum, o);
  if ((tid & 63) == 0) reds[tid >> 6] = sum;
  __syncthreads();
  sum = reds[0] + reds[1] + reds[2] + reds[3];
  const float inv = 1.0f / sum;
  short4v o4;
  #pragma unroll
  for (int j = 0; j < 4; ++j) o4[j] = (short)f2b(v[j] * inv);
  *(short4v*)(P + ((size_t)(b * 1024 + m)) * 1024 + tid * 4) = o4;
}

extern "C" void kernel_launch(void* const* d_in, const int* in_sizes, int n_in,
                              void* d_out, int out_size, void* d_ws, size_t ws_size,
                              hipStream_t stream) {
  const float* q = (const float*)d_in[0];
  const float* k = (const float*)d_in[1];
  const float* v = (const float*)d_in[2];
  ushort_t* wsA = (ushort_t*)d_ws;
  ushort_t* wsB = wsA + (size_t)33554432;          // 64 MiB in
  ushort_t* wsP = wsB + (size_t)33554432;          // 128 MiB in
  const size_t P1OFF = 16777216;                   // patch-1 offset within A/B regions (elems)
  const size_t PP1   = 2097152;                    // patch-1 offset within P region (elems)
  float* part = (float*)(wsP + PP1);               // QK-p0 split-K partials (64 MiB), overlaid on P-p1 region

  // tokenize Q, K
  tok_qk<8, 8, 0,   1024><<<8192,  256, 0, stream>>>(q, wsA);
  tok_qk<4, 4, 128, 4096><<<16384, 256, 0, stream>>>(q, wsA + P1OFF);
  tok_qk<8, 8, 0,   1024><<<8192,  256, 0, stream>>>(k, wsB);
  tok_qk<4, 4, 128, 4096><<<16384, 256, 0, stream>>>(k, wsB + P1OFF);

  // QK p0: split-K=8 -> fp32 partials [ks][b][1024][1024]; fused combine+softmax
  gemm_pipe<2, 8, 1024, 1, 1, 0><<<dim3(4, 4, 16), 512, 0, stream>>>(
      wsA, wsB, (size_t)1024 * 8192, (size_t)1024 * 8192, 8192, 16,
      part, (size_t)1048576, 0.011048543456039806f);
  softmax_combine_p0<<<2048, 256, 0, stream>>>(part, wsP);

  // QK p1 (overwrites partial region AFTER combine consumed it)
  gemm_pipe<0, 1, 4096, 1, 1, 0><<<dim3(16, 16, 2), 512, 0, stream>>>(
      wsA + P1OFF, wsB + P1OFF, (size_t)4096 * 2048, (size_t)4096 * 2048, 2048, 32,
      wsP + PP1, (size_t)4096 * 4096, 0.022097086912079612f);
  softmax_rows<4096><<<8192, 256, 0, stream>>>(wsP + PP1);

  // tokenize V transposed into A region (Q tokens no longer needed)
  tok_vt<8, 8, 0,   1024><<<8192,  256, 0, stream>>>(v, wsA);
  tok_vt<4, 4, 128, 4096><<<16384, 256, 0, stream>>>(v, wsA + P1OFF);

  // O = P * V -> scatter fp32 into d_out
  gemm_pipe<1, 1, 0, 8, 8, 0><<<dim3(32, 4, 2), 512, 0, stream>>>(
      wsP, wsA, (size_t)1024 * 1024, (size_t)8192 * 1024, 1024, 16, d_out, 0, 1.0f);
  gemm_pipe<1, 1, 0, 4, 4, 128><<<dim3(8, 16, 2), 512, 0, stream>>>(
      wsP + PP1, wsA + P1OFF, (size_t)4096 * 4096, (size_t)2048 * 4096, 4096, 64, d_out, 0, 1.0f);
}

// Round 6
// 651.265 us; speedup vs baseline: 1.3820x; 1.0016x over previous
//
#include <hip/hip_runtime.h>
#include <hip/hip_bf16.h>
#include <stdint.h>

typedef unsigned short ushort_t;
typedef unsigned int uint_t;

typedef __bf16 bf16x8 __attribute__((ext_vector_type(8)));
typedef float f32x4 __attribute__((ext_vector_type(4)));
typedef short short4v __attribute__((ext_vector_type(4)));

typedef const __attribute__((address_space(1))) void gv_t;
typedef __attribute__((address_space(3))) void lv_t;

__device__ __forceinline__ ushort_t f2b(float f) {
  uint_t u = __builtin_bit_cast(uint_t, f);
  u += 0x7FFFu + ((u >> 16) & 1u);   // round-to-nearest-even
  return (ushort_t)(u >> 16);
}
__device__ __forceinline__ float b2f(ushort_t s) {
  return __builtin_bit_cast(float, (uint_t)s << 16);
}
constexpr int ilog2c(int x) { return x <= 1 ? 0 : 1 + ilog2c(x >> 1); }

constexpr int Tt = 16, Cc = 256, Hh = 64, Ww = 64, DKc = 128;

// ---------------- tokenize Q/K: (B*T,128,H,W) slice -> (b, n, d) bf16 row-major ----------------
template<int PH, int PW, int CBASE, int NP>
__global__ __launch_bounds__(256) void tok_qk(const float* __restrict__ src, ushort_t* __restrict__ dst) {
  constexpr int OHN = Hh / PH, OWN = Ww / PW, DP = DKc * PH * PW, OHW = OHN * OWN;
  const int id = blockIdx.x * 256 + threadIdx.x;
  const int py = id & (PH - 1);
  const int c  = (id >> ilog2c(PH)) & (DKc - 1);
  const int n  = (id >> (ilog2c(PH) + 7)) & (NP - 1);
  const int b  = id >> (ilog2c(PH) + 7 + ilog2c(NP));
  const int t  = n >> ilog2c(OHW);
  const int rem = n & (OHW - 1);
  const int oh = rem >> ilog2c(OWN);
  const int ow = rem & (OWN - 1);
  const float* s = src + (((size_t)((b * Tt + t) * Cc + CBASE + c)) << 12)
                       + ((oh * PH + py) << 6) + ow * PW;
  ushort_t* d = dst + (size_t)(b * NP + n) * DP + (c * PH + py) * PW;
  float4 f0 = *(const float4*)s;
  short4v o0; o0[0] = f2b(f0.x); o0[1] = f2b(f0.y); o0[2] = f2b(f0.z); o0[3] = f2b(f0.w);
  *(short4v*)d = o0;
  if constexpr (PW == 8) {
    float4 f1 = *(const float4*)(s + 4);
    short4v o1; o1[0] = f2b(f1.x); o1[1] = f2b(f1.y); o1[2] = f2b(f1.z); o1[3] = f2b(f1.w);
    *(short4v*)(d + 4) = o1;
  }
}

// ---------------- tokenize V transposed: -> (b, d, n) bf16 row-major ----------------
template<int PH, int PW, int CBASE, int NP>
__global__ __launch_bounds__(256) void tok_vt(const float* __restrict__ src, ushort_t* __restrict__ dst) {
  constexpr int OHN = Hh / PH, OWN = Ww / PW, DP = DKc * PH * PW;
  constexpr int CH = PW, NCH = OWN / CH;
  const int id  = blockIdx.x * 256 + threadIdx.x;
  const int owc = id & (NCH - 1);
  const int oh  = (id >> ilog2c(NCH)) & (OHN - 1);
  const int t   = (id >> (ilog2c(NCH) + ilog2c(OHN))) & (Tt - 1);
  const int dd  = (id >> (ilog2c(NCH) + ilog2c(OHN) + 4)) & (DP - 1);
  const int b   = id >> (ilog2c(NCH) + ilog2c(OHN) + 4 + ilog2c(DP));
  const int c   = dd >> ilog2c(PH * PW);
  const int py  = (dd >> ilog2c(PW)) & (PH - 1);
  const int px  = dd & (PW - 1);
  const float* s = src + (((size_t)((b * Tt + t) * Cc + CBASE + c)) << 12)
                       + ((oh * PH + py) << 6) + px;
  const int n0 = (t * OHN + oh) * OWN + owc * CH;
  ushort_t* d = dst + (size_t)(b * DP + dd) * NP + n0;
  short4v o;
  #pragma unroll
  for (int j = 0; j < 4; ++j) o[j] = f2b(s[(owc * CH + j) * PW]);
  *(short4v*)d = o;
  if constexpr (CH == 8) {
    short4v o2;
    #pragma unroll
    for (int j = 0; j < 4; ++j) o2[j] = f2b(s[(owc * CH + 4 + j) * PW]);
    *(short4v*)(d + 4) = o2;
  }
}

__device__ __forceinline__ void waitvm8() { asm volatile("s_waitcnt vmcnt(8)" ::: "memory"); }
__device__ __forceinline__ void waitvm6() { asm volatile("s_waitcnt vmcnt(6)" ::: "memory"); }
__device__ __forceinline__ void waitvm0() { asm volatile("s_waitcnt vmcnt(0)" ::: "memory"); }

// ---- 256x256/BK=64 double-buffered NT GEMM, 4 quadrant-phases/K-tile, read-ahead frags ----
// No sched_barrier pins: ordering anchored by "memory"-clobbered vmcnt asm + raw s_barrier +
// data deps; compiler free to emit counted lgkm waits and interleave (m141 lesson).
// EPI 0: bf16 scores*scale -> P ; EPI 1: fp32 from_tokens scatter ; EPI 2: fp32 split-K partial
template<int EPI, int KSPLIT, int NP, int PH, int PW, int CBASE>
__global__ __launch_bounds__(512, 2)
void gemm_pipe(const ushort_t* __restrict__ A, const ushort_t* __restrict__ B,
               size_t aBatch, size_t bBatch, int ldk, int nt,
               void* __restrict__ outPtr, size_t oBatch, float scale) {
  __shared__ __align__(16) ushort_t As[2 * 256 * 64];
  __shared__ __align__(16) ushort_t Bs[2 * 256 * 64];

  const int tid = threadIdx.x;
  const int w = tid >> 6, l = tid & 63;
  const int wm = w >> 2, wn = w & 3;
  const int lr = l & 15, lk = l >> 4;
  const int srow8 = tid >> 3;                            // staging row within 64-row round
  const int gcolS = (((tid & 7) ^ (srow8 & 7)) << 3);    // pre-swizzled global col (bf16)
  const int sw0 = ((lk ^ (lr & 7)) << 4);                // swizzled byte slot, ks=0
  const int sw1 = sw0 ^ 64;                              // ks=1

  // XCD-aware bijective swizzle (grid always a multiple of 8)
  const int gx = gridDim.x, gy = gridDim.y, gz = gridDim.z;
  int id = (blockIdx.z * gy + blockIdx.y) * gx + blockIdx.x;
  const int cpx = (gx * gy * gz) >> 3;
  id = (id & 7) * cpx + (id >> 3);
  const int bx = id % gx;
  const int rst = id / gx;
  const int by = rst % gy;
  const int bz = rst / gy;

  int batch = bz, ks = 0;
  if constexpr (KSPLIT > 1) { batch = bz / KSPLIT; ks = bz - batch * KSPLIT; }

  const int rowBase = by * 256, colBase = bx * 256;
  const ushort_t* Ab = A + (size_t)batch * aBatch + (size_t)ks * nt * 64;
  const ushort_t* Bb = B + (size_t)batch * bBatch + (size_t)ks * nt * 64;

  f32x4 acc[8][4] = {};
  bf16x8 A0[8], A1[8], B0[4], B1[4];   // frag regs: [mi*2+ks] / [ni*2+ks]

  auto stgA = [&](int buf, int r, int kt) {
    const int rr = r * 64 + srow8;
    const ushort_t* g = Ab + (size_t)(rowBase + rr) * ldk + kt * 64 + gcolS;
    __builtin_amdgcn_global_load_lds((gv_t*)g, (lv_t*)((char*)As + buf * 32768 + r * 8192 + w * 1024), 16, 0, 0);
  };
  auto stgB = [&](int buf, int r, int kt) {
    const int rr = r * 64 + srow8;
    const ushort_t* g = Bb + (size_t)(colBase + rr) * ldk + kt * 64 + gcolS;
    __builtin_amdgcn_global_load_lds((gv_t*)g, (lv_t*)((char*)Bs + buf * 32768 + r * 8192 + w * 1024), 16, 0, 0);
  };

  auto rdA_ = [&](int buf, int mh, bf16x8* dst) {
    const char* b0p = (const char*)As + buf * 32768 + (wm * 128 + mh * 64 + lr) * 128;
#pragma unroll
    for (int mi = 0; mi < 4; ++mi) {
      dst[mi * 2 + 0] = *(const bf16x8*)(b0p + mi * 2048 + sw0);
      dst[mi * 2 + 1] = *(const bf16x8*)(b0p + mi * 2048 + sw1);
    }
  };
  auto rdB_ = [&](int buf, int nh, bf16x8* dst) {
    const char* b0p = (const char*)Bs + buf * 32768 + (wn * 64 + nh * 32 + lr) * 128;
#pragma unroll
    for (int ni = 0; ni < 2; ++ni) {
      dst[ni * 2 + 0] = *(const bf16x8*)(b0p + ni * 2048 + sw0);
      dst[ni * 2 + 1] = *(const bf16x8*)(b0p + ni * 2048 + sw1);
    }
  };
  auto mmq = [&](const bf16x8* a, const bf16x8* b, int mh, int nh) {
    __builtin_amdgcn_s_setprio(1);
#pragma unroll
    for (int mi = 0; mi < 4; ++mi)
#pragma unroll
      for (int ni = 0; ni < 2; ++ni) {
        f32x4& cc = acc[mh * 4 + mi][nh * 2 + ni];
        cc = __builtin_amdgcn_mfma_f32_16x16x32_bf16(a[mi * 2 + 0], b[ni * 2 + 0], cc, 0, 0, 0);
        cc = __builtin_amdgcn_mfma_f32_16x16x32_bf16(a[mi * 2 + 1], b[ni * 2 + 1], cc, 0, 0, 0);
      }
    __builtin_amdgcn_s_setprio(0);
  };

  // prologue: tile0 full (8 loads) + tile1 full (8 loads); drain tile0 only
  stgA(0, 0, 0); stgA(0, 1, 0); stgA(0, 2, 0); stgA(0, 3, 0);
  stgB(0, 0, 0); stgB(0, 1, 0); stgB(0, 2, 0); stgB(0, 3, 0);
  stgA(1, 0, 1); stgA(1, 2, 1);
  stgB(1, 0, 1); stgB(1, 1, 1); stgB(1, 2, 1); stgB(1, 3, 1);
  stgA(1, 1, 1); stgA(1, 3, 1);
  waitvm8();
  __builtin_amdgcn_s_barrier();
  rdA_(0, 0, A0);
  rdB_(0, 0, B0);

  for (int t = 0; t < nt; ++t) {
    const int c = t & 1;
    // ---- P0: MFMA (mh0,nh0); read-ahead B1 ----
    rdB_(c, 1, B1);
    __builtin_amdgcn_s_barrier();
    mmq(A0, B0, 0, 0);
    __builtin_amdgcn_s_barrier();
    // ---- P1: MFMA (mh0,nh1); read-ahead A1; stage t+2 A rounds 0,2 ----
    rdA_(c, 1, A1);
    if (t + 2 < nt) { stgA(c, 0, t + 2); stgA(c, 2, t + 2); }
    __builtin_amdgcn_s_barrier();
    mmq(A0, B1, 0, 1);
    __builtin_amdgcn_s_barrier();
    // ---- P2: MFMA (mh1,nh0); stage t+2 B all; counted vmcnt guarantees t+1 landed ----
    if (t + 2 < nt) {
      stgB(c, 0, t + 2); stgB(c, 1, t + 2); stgB(c, 2, t + 2); stgB(c, 3, t + 2);
      waitvm6();
    } else if (t + 1 < nt) {
      waitvm0();
    }
    __builtin_amdgcn_s_barrier();
    mmq(A1, B0, 1, 0);
    __builtin_amdgcn_s_barrier();
    // ---- P3: MFMA (mh1,nh1); read-ahead next tile's A0,B0; stage t+2 A rounds 1,3 ----
    if (t + 1 < nt) { rdA_(c ^ 1, 0, A0); rdB_(c ^ 1, 0, B0); }
    if (t + 2 < nt) { stgA(c, 1, t + 2); stgA(c, 3, t + 2); }
    __builtin_amdgcn_s_barrier();
    mmq(A1, B1, 1, 1);
    __builtin_amdgcn_s_barrier();
  }

  if constexpr (EPI == 0) {
    ushort_t* P = (ushort_t*)outPtr + (size_t)batch * oBatch;
#pragma unroll
    for (int mi = 0; mi < 8; ++mi) {
      const int row0 = rowBase + wm * 128 + mi * 16 + lk * 4;
#pragma unroll
      for (int ni = 0; ni < 4; ++ni) {
        const int col = colBase + wn * 64 + ni * 16 + lr;
#pragma unroll
        for (int r = 0; r < 4; ++r)
          P[(size_t)(row0 + r) * NP + col] = f2b(acc[mi][ni][r] * scale);
      }
    }
  } else if constexpr (EPI == 1) {
    float* O = (float*)outPtr;
    constexpr int OWN = Ww / PW;
    constexpr int OHW = (Hh / PH) * OWN;
    constexpr int PHPW = PH * PW;
#pragma unroll
    for (int mi = 0; mi < 8; ++mi) {
#pragma unroll
      for (int ni = 0; ni < 4; ++ni) {
        const int d = colBase + wn * 64 + ni * 16 + lr;
        const int c   = d >> ilog2c(PHPW);
        const int pyx = d & (PHPW - 1);
        const int py  = pyx >> ilog2c(PW);
        const int px  = pyx & (PW - 1);
#pragma unroll
        for (int r = 0; r < 4; ++r) {
          const int qq = rowBase + wm * 128 + mi * 16 + lk * 4 + r;
          const int tt = qq >> ilog2c(OHW);
          const int rm = qq & (OHW - 1);
          const int oh = rm >> ilog2c(OWN);
          const int ow = rm & (OWN - 1);
          size_t off = (((size_t)((batch * Tt + tt) * Cc + CBASE + c)) << 12)
                     + ((oh * PH + py) << 6) + ow * PW + px;
          O[off] = acc[mi][ni][r];
        }
      }
    }
  } else {
    const int nb = gz / KSPLIT;
    float* O = (float*)outPtr + ((size_t)ks * nb + batch) * oBatch;
#pragma unroll
    for (int mi = 0; mi < 8; ++mi) {
      const int row0 = rowBase + wm * 128 + mi * 16 + lk * 4;
#pragma unroll
      for (int ni = 0; ni < 4; ++ni) {
        const int col = colBase + wn * 64 + ni * 16 + lr;
#pragma unroll
        for (int r = 0; r < 4; ++r)
          O[(size_t)(row0 + r) * NP + col] = acc[mi][ni][r] * scale;
      }
    }
  }
}

// ---------------- row softmax over bf16 scores, in place ----------------
template<int NP>
__global__ __launch_bounds__(256) void softmax_rows(ushort_t* __restrict__ P) {
  constexpr int PER = NP / 256;
  constexpr int CH  = NP / 1024;
  ushort_t* row = P + (size_t)blockIdx.x * NP;
  const int tid = threadIdx.x;
  float v[PER];
  #pragma unroll
  for (int j = 0; j < CH; ++j) {
    short4v s = *(const short4v*)(row + j * 1024 + tid * 4);
    #pragma unroll
    for (int jj = 0; jj < 4; ++jj) v[4 * j + jj] = b2f((ushort_t)s[jj]);
  }
  float m = -1e30f;
  #pragma unroll
  for (int j = 0; j < PER; ++j) m = fmaxf(m, v[j]);
  #pragma unroll
  for (int o = 32; o >= 1; o >>= 1) m = fmaxf(m, __shfl_xor(m, o));
  __shared__ float redm[4];
  if ((tid & 63) == 0) redm[tid >> 6] = m;
  __syncthreads();
  m = fmaxf(fmaxf(redm[0], redm[1]), fmaxf(redm[2], redm[3]));
  float sum = 0.f;
  #pragma unroll
  for (int j = 0; j < PER; ++j) { v[j] = __expf(v[j] - m); sum += v[j]; }
  #pragma unroll
  for (int o = 32; o >= 1; o >>= 1) sum += __shfl_xor(sum, o);
  __shared__ float reds[4];
  if ((tid & 63) == 0) reds[tid >> 6] = sum;
  __syncthreads();
  sum = reds[0] + reds[1] + reds[2] + reds[3];
  const float inv = 1.0f / sum;
  #pragma unroll
  for (int j = 0; j < CH; ++j) {
    short4v o;
    #pragma unroll
    for (int jj = 0; jj < 4; ++jj) o[jj] = (short)f2b(v[4 * j + jj] * inv);
    *(short4v*)(row + j * 1024 + tid * 4) = o;
  }
}

// ---------------- combine 8 fp32 split-K partials + softmax -> bf16 P (patch 0, NP=1024) ----------------
__global__ __launch_bounds__(256) void softmax_combine_p0(const float* __restrict__ part,
                                                          ushort_t* __restrict__ P) {
  const int tid = threadIdx.x;
  const int b = blockIdx.x >> 10;          // batch
  const int m = blockIdx.x & 1023;         // row within batch
  float v[4] = {0.f, 0.f, 0.f, 0.f};
  #pragma unroll
  for (int ks = 0; ks < 8; ++ks) {
    const float* r = part + ((size_t)(ks * 2 + b) * 1024 + m) * 1024 + tid * 4;
    float4 a = *(const float4*)r;
    v[0] += a.x; v[1] += a.y; v[2] += a.z; v[3] += a.w;
  }
  float mx = fmaxf(fmaxf(v[0], v[1]), fmaxf(v[2], v[3]));
  #pragma unroll
  for (int o = 32; o >= 1; o >>= 1) mx = fmaxf(mx, __shfl_xor(mx, o));
  __shared__ float redm[4], reds[4];
  if ((tid & 63) == 0) redm[tid >> 6] = mx;
  __syncthreads();
  mx = fmaxf(fmaxf(redm[0], redm[1]), fmaxf(redm[2], redm[3]));
  float sum = 0.f;
  #pragma unroll
  for (int j = 0; j < 4; ++j) { v[j] = __expf(v[j] - mx); sum += v[j]; }
  #pragma unroll
  for (int o = 32; o >= 1; o >>= 1) sum += __shfl_xor(sum, o);
  if ((tid & 63) == 0) reds[tid >> 6] = sum;
  __syncthreads();
  sum = reds[0] + reds[1] + reds[2] + reds[3];
  const float inv = 1.0f / sum;
  short4v o4;
  #pragma unroll
  for (int j = 0; j < 4; ++j) o4[j] = (short)f2b(v[j] * inv);
  *(short4v*)(P + ((size_t)(b * 1024 + m)) * 1024 + tid * 4) = o4;
}

extern "C" void kernel_launch(void* const* d_in, const int* in_sizes, int n_in,
                              void* d_out, int out_size, void* d_ws, size_t ws_size,
                              hipStream_t stream) {
  const float* q = (const float*)d_in[0];
  const float* k = (const float*)d_in[1];
  const float* v = (const float*)d_in[2];
  ushort_t* wsA = (ushort_t*)d_ws;
  ushort_t* wsB = wsA + (size_t)33554432;          // 64 MiB in
  ushort_t* wsP = wsB + (size_t)33554432;          // 128 MiB in
  const size_t P1OFF = 16777216;                   // patch-1 offset within A/B regions (elems)
  const size_t PP1   = 2097152;                    // patch-1 offset within P region (elems)
  float* part = (float*)(wsP + PP1);               // QK-p0 split-K partials (64 MiB), overlaid on P-p1 region

  // tokenize Q, K
  tok_qk<8, 8, 0,   1024><<<8192,  256, 0, stream>>>(q, wsA);
  tok_qk<4, 4, 128, 4096><<<16384, 256, 0, stream>>>(q, wsA + P1OFF);
  tok_qk<8, 8, 0,   1024><<<8192,  256, 0, stream>>>(k, wsB);
  tok_qk<4, 4, 128, 4096><<<16384, 256, 0, stream>>>(k, wsB + P1OFF);

  // QK p0: split-K=8 -> fp32 partials [ks][b][1024][1024]; fused combine+softmax
  gemm_pipe<2, 8, 1024, 1, 1, 0><<<dim3(4, 4, 16), 512, 0, stream>>>(
      wsA, wsB, (size_t)1024 * 8192, (size_t)1024 * 8192, 8192, 16,
      part, (size_t)1048576, 0.011048543456039806f);
  softmax_combine_p0<<<2048, 256, 0, stream>>>(part, wsP);

  // QK p1 (overwrites partial region AFTER combine consumed it)
  gemm_pipe<0, 1, 4096, 1, 1, 0><<<dim3(16, 16, 2), 512, 0, stream>>>(
      wsA + P1OFF, wsB + P1OFF, (size_t)4096 * 2048, (size_t)4096 * 2048, 2048, 32,
      wsP + PP1, (size_t)4096 * 4096, 0.022097086912079612f);
  softmax_rows<4096><<<8192, 256, 0, stream>>>(wsP + PP1);

  // tokenize V transposed into A region (Q tokens no longer needed)
  tok_vt<8, 8, 0,   1024><<<8192,  256, 0, stream>>>(v, wsA);
  tok_vt<4, 4, 128, 4096><<<16384, 256, 0, stream>>>(v, wsA + P1OFF);

  // O = P * V -> scatter fp32 into d_out
  gemm_pipe<1, 1, 0, 8, 8, 0><<<dim3(32, 4, 2), 512, 0, stream>>>(
      wsP, wsA, (size_t)1024 * 1024, (size_t)8192 * 1024, 1024, 16, d_out, 0, 1.0f);
  gemm_pipe<1, 1, 0, 4, 4, 128><<<dim3(8, 16, 2), 512, 0, stream>>>(
      wsP + PP1, wsA + P1OFF, (size_t)4096 * 4096, (size_t)2048 * 4096, 4096, 64, d_out, 0, 1.0f);
}

// Round 8
// 609.799 us; speedup vs baseline: 1.4760x; 1.0680x over previous
//
#include <hip/hip_runtime.h>
#include <hip/hip_bf16.h>
#include <stdint.h>

typedef unsigned short ushort_t;
typedef unsigned int uint_t;

typedef __bf16 bf16x8 __attribute__((ext_vector_type(8)));
typedef float f32x4 __attribute__((ext_vector_type(4)));
typedef short short4v __attribute__((ext_vector_type(4)));

typedef const __attribute__((address_space(1))) void gv_t;
typedef __attribute__((address_space(3))) void lv_t;

__device__ __forceinline__ ushort_t f2b(float f) {
  uint_t u = __builtin_bit_cast(uint_t, f);
  u += 0x7FFFu + ((u >> 16) & 1u);   // round-to-nearest-even
  return (ushort_t)(u >> 16);
}
__device__ __forceinline__ float b2f(ushort_t s) {
  return __builtin_bit_cast(float, (uint_t)s << 16);
}
constexpr int ilog2c(int x) { return x <= 1 ? 0 : 1 + ilog2c(x >> 1); }

constexpr int Tt = 16, Cc = 256, Hh = 64, Ww = 64, DKc = 128;

// ---------------- tokenize Q/K: (B*T,128,H,W) slice -> (b, n, d) bf16 row-major ----------------
template<int PH, int PW, int CBASE, int NP>
__global__ __launch_bounds__(256) void tok_qk(const float* __restrict__ src, ushort_t* __restrict__ dst) {
  constexpr int OHN = Hh / PH, OWN = Ww / PW, DP = DKc * PH * PW, OHW = OHN * OWN;
  const int id = blockIdx.x * 256 + threadIdx.x;
  const int py = id & (PH - 1);
  const int c  = (id >> ilog2c(PH)) & (DKc - 1);
  const int n  = (id >> (ilog2c(PH) + 7)) & (NP - 1);
  const int b  = id >> (ilog2c(PH) + 7 + ilog2c(NP));
  const int t  = n >> ilog2c(OHW);
  const int rem = n & (OHW - 1);
  const int oh = rem >> ilog2c(OWN);
  const int ow = rem & (OWN - 1);
  const float* s = src + (((size_t)((b * Tt + t) * Cc + CBASE + c)) << 12)
                       + ((oh * PH + py) << 6) + ow * PW;
  ushort_t* d = dst + (size_t)(b * NP + n) * DP + (c * PH + py) * PW;
  float4 f0 = *(const float4*)s;
  short4v o0; o0[0] = f2b(f0.x); o0[1] = f2b(f0.y); o0[2] = f2b(f0.z); o0[3] = f2b(f0.w);
  *(short4v*)d = o0;
  if constexpr (PW == 8) {
    float4 f1 = *(const float4*)(s + 4);
    short4v o1; o1[0] = f2b(f1.x); o1[1] = f2b(f1.y); o1[2] = f2b(f1.z); o1[3] = f2b(f1.w);
    *(short4v*)(d + 4) = o1;
  }
}

// ---------------- tokenize V transposed: -> (b, d, n) bf16 row-major ----------------
template<int PH, int PW, int CBASE, int NP>
__global__ __launch_bounds__(256) void tok_vt(const float* __restrict__ src, ushort_t* __restrict__ dst) {
  constexpr int OHN = Hh / PH, OWN = Ww / PW, DP = DKc * PH * PW;
  constexpr int CH = PW, NCH = OWN / CH;
  const int id  = blockIdx.x * 256 + threadIdx.x;
  const int owc = id & (NCH - 1);
  const int oh  = (id >> ilog2c(NCH)) & (OHN - 1);
  const int t   = (id >> (ilog2c(NCH) + ilog2c(OHN))) & (Tt - 1);
  const int dd  = (id >> (ilog2c(NCH) + ilog2c(OHN) + 4)) & (DP - 1);
  const int b   = id >> (ilog2c(NCH) + ilog2c(OHN) + 4 + ilog2c(DP));
  const int c   = dd >> ilog2c(PH * PW);
  const int py  = (dd >> ilog2c(PW)) & (PH - 1);
  const int px  = dd & (PW - 1);
  const float* s = src + (((size_t)((b * Tt + t) * Cc + CBASE + c)) << 12)
                       + ((oh * PH + py) << 6) + px;
  const int n0 = (t * OHN + oh) * OWN + owc * CH;
  ushort_t* d = dst + (size_t)(b * DP + dd) * NP + n0;
  short4v o;
  #pragma unroll
  for (int j = 0; j < 4; ++j) o[j] = f2b(s[(owc * CH + j) * PW]);
  *(short4v*)d = o;
  if constexpr (CH == 8) {
    short4v o2;
    #pragma unroll
    for (int j = 0; j < 4; ++j) o2[j] = f2b(s[(owc * CH + 4 + j) * PW]);
    *(short4v*)(d + 4) = o2;
  }
}

__device__ __forceinline__ void waitvm8() { asm volatile("s_waitcnt vmcnt(8)" ::: "memory"); }
__device__ __forceinline__ void waitvm6() { asm volatile("s_waitcnt vmcnt(6)" ::: "memory"); }
__device__ __forceinline__ void waitvm0() { asm volatile("s_waitcnt vmcnt(0)" ::: "memory"); }

// ---- 256x256/BK=64 double-buffered NT GEMM, 4 quadrant-phases/K-tile ----
// ds_reads: base-reg + compile-time imm offsets; staging: persistent pointers,
// parity-explicit elemOff (0 / 64), advanced +128 once per unrolled K-tile pair.
// 4 end-barriers + 1 counted vmcnt(6) per K-tile; read-ahead frags one phase early.
// EPI 0: bf16 scores*scale -> P ; EPI 1: fp32 from_tokens scatter ; EPI 2: fp32 split-K partial
template<int EPI, int KSPLIT, int LDK, int NP, int PH, int PW, int CBASE>
__global__ __launch_bounds__(512, 2)
void gemm_pipe(const ushort_t* __restrict__ A, const ushort_t* __restrict__ B,
               size_t aBatch, size_t bBatch, int nt,
               void* __restrict__ outPtr, size_t oBatch, float scale) {
  __shared__ __align__(16) ushort_t As[2 * 256 * 64];
  __shared__ __align__(16) ushort_t Bs[2 * 256 * 64];

  const int tid = threadIdx.x;
  const int w = tid >> 6, l = tid & 63;
  const int wm = w >> 2, wn = w & 3;
  const int lr = l & 15, lk = l >> 4;
  const int srow8 = tid >> 3;                            // staging row within 64-row round
  const int gcolS = (((tid & 7) ^ (srow8 & 7)) << 3);    // pre-swizzled global col (bf16)
  const int sw0 = ((lk ^ (lr & 7)) << 4);                // swizzled byte slot, ks=0
  const int sw1 = sw0 ^ 64;                              // ks=1

  // XCD-aware bijective swizzle (grid always a multiple of 8)
  const int gx = gridDim.x, gy = gridDim.y, gz = gridDim.z;
  int id = (blockIdx.z * gy + blockIdx.y) * gx + blockIdx.x;
  const int cpx = (gx * gy * gz) >> 3;
  id = (id & 7) * cpx + (id >> 3);
  const int bx = id % gx;
  const int rst = id / gx;
  const int by = rst % gy;
  const int bz = rst / gy;

  int batch = bz, ks = 0;
  if constexpr (KSPLIT > 1) { batch = bz / KSPLIT; ks = bz - batch * KSPLIT; }

  const int rowBase = by * 256, colBase = bx * 256;
  const ushort_t* Ab = A + (size_t)batch * aBatch + (size_t)ks * nt * 64;
  const ushort_t* Bb = B + (size_t)batch * bBatch + (size_t)ks * nt * 64;

  // persistent staging pointers: base corresponds to K-tile (pair_start + 2)
  const ushort_t* pA[4];
  const ushort_t* pB[4];
#pragma unroll
  for (int r = 0; r < 4; ++r) {
    pA[r] = Ab + (size_t)(rowBase + r * 64 + srow8) * LDK + gcolS;
    pB[r] = Bb + (size_t)(colBase + r * 64 + srow8) * LDK + gcolS;
  }

  // LDS read base pointers (all loop offsets become compile-time immediates)
  const char* ArdBase0 = (const char*)As + (wm * 128 + lr) * 128 + sw0;
  const char* ArdBase1 = (const char*)As + (wm * 128 + lr) * 128 + sw1;
  const char* BrdBase0 = (const char*)Bs + (wn * 64 + lr) * 128 + sw0;
  const char* BrdBase1 = (const char*)Bs + (wn * 64 + lr) * 128 + sw1;

  f32x4 acc[8][4] = {};
  bf16x8 Am0[8], Am1[8], Bn0[4], Bn1[4];   // [mi*2+ks] / [ni*2+ks]

  auto stgA = [&](int bufB, int r, int elemOff) {
    __builtin_amdgcn_global_load_lds((gv_t*)(pA[r] + elemOff),
        (lv_t*)((char*)As + bufB + r * 8192 + w * 1024), 16, 0, 0);
  };
  auto stgB = [&](int bufB, int r, int elemOff) {
    __builtin_amdgcn_global_load_lds((gv_t*)(pB[r] + elemOff),
        (lv_t*)((char*)Bs + bufB + r * 8192 + w * 1024), 16, 0, 0);
  };
  auto rdA = [&](int off, bf16x8* dst) {
#pragma unroll
    for (int mi = 0; mi < 4; ++mi) {
      dst[mi * 2 + 0] = *(const bf16x8*)(ArdBase0 + off + mi * 2048);
      dst[mi * 2 + 1] = *(const bf16x8*)(ArdBase1 + off + mi * 2048);
    }
  };
  auto rdB = [&](int off, bf16x8* dst) {
#pragma unroll
    for (int ni = 0; ni < 2; ++ni) {
      dst[ni * 2 + 0] = *(const bf16x8*)(BrdBase0 + off + ni * 2048);
      dst[ni * 2 + 1] = *(const bf16x8*)(BrdBase1 + off + ni * 2048);
    }
  };
  auto mmq = [&](const bf16x8* a, const bf16x8* b, int mh, int nh) {
    __builtin_amdgcn_s_setprio(1);
#pragma unroll
    for (int mi = 0; mi < 4; ++mi)
#pragma unroll
      for (int ni = 0; ni < 2; ++ni) {
        f32x4& cc = acc[mh * 4 + mi][nh * 2 + ni];
        cc = __builtin_amdgcn_mfma_f32_16x16x32_bf16(a[mi * 2 + 0], b[ni * 2 + 0], cc, 0, 0, 0);
        cc = __builtin_amdgcn_mfma_f32_16x16x32_bf16(a[mi * 2 + 1], b[ni * 2 + 1], cc, 0, 0, 0);
      }
    __builtin_amdgcn_s_setprio(0);
  };

  // prologue: tile0 (8 loads) then tile1 (8 loads); advance base to K-tile 2; drain tile0 only
#pragma unroll
  for (int r = 0; r < 4; ++r) stgA(0, r, 0);
#pragma unroll
  for (int r = 0; r < 4; ++r) stgB(0, r, 0);
#pragma unroll
  for (int r = 0; r < 4; ++r) stgA(32768, r, 64);
#pragma unroll
  for (int r = 0; r < 4; ++r) stgB(32768, r, 64);
#pragma unroll
  for (int r = 0; r < 4; ++r) { pA[r] += 128; pB[r] += 128; }
  waitvm8();
  __builtin_amdgcn_s_barrier();
  rdA(0, Am0);
  rdB(0, Bn0);

// TB(T, BUFB, EOFF, ADV): one K-tile. Stages tile T+2 at elemOff EOFF from the
// pair base; ADV=1 (odd tile of the pair) advances the base by +128 elems.
#define TB(T, BUFB, EOFF, ADV) do {                                             \
    const int OB = (BUFB) ^ 32768;                                              \
    /* P0: MFMA q(0,0); read-ahead B-half1 */                                   \
    rdB((BUFB) + 4096, Bn1);                                                    \
    mmq(Am0, Bn0, 0, 0);                                                        \
    __builtin_amdgcn_s_barrier();                                               \
    /* P1: MFMA q(0,1); read-ahead A-half1; stage t+2 A rounds 0,2 */           \
    rdA((BUFB) + 8192, Am1);                                                    \
    if ((T) + 2 < nt) { stgA((BUFB), 0, (EOFF)); stgA((BUFB), 2, (EOFF)); }     \
    mmq(Am0, Bn1, 0, 1);                                                        \
    __builtin_amdgcn_s_barrier();                                               \
    /* P2: MFMA q(1,0); stage t+2 B all; counted drain before end barrier */    \
    if ((T) + 2 < nt) { stgB((BUFB), 0, (EOFF)); stgB((BUFB), 1, (EOFF));       \
                        stgB((BUFB), 2, (EOFF)); stgB((BUFB), 3, (EOFF)); }     \
    mmq(Am1, Bn0, 1, 0);                                                        \
    if ((T) + 2 < nt) waitvm6(); else if ((T) + 1 < nt) waitvm0();              \
    __builtin_amdgcn_s_barrier();                                               \
    /* P3: MFMA q(1,1); read-ahead next tile A0,B0; stage t+2 A rounds 1,3 */   \
    if ((T) + 1 < nt) { rdA(OB, Am0); rdB(OB, Bn0); }                           \
    if ((T) + 2 < nt) {                                                         \
      stgA((BUFB), 1, (EOFF)); stgA((BUFB), 3, (EOFF));                         \
      if (ADV) {                                                                \
        _Pragma("unroll")                                                       \
        for (int r = 0; r < 4; ++r) { pA[r] += 128; pB[r] += 128; }             \
      }                                                                         \
    }                                                                           \
    mmq(Am1, Bn1, 1, 1);                                                        \
    __builtin_amdgcn_s_barrier();                                               \
  } while (0)

  for (int t = 0; t < nt; t += 2) {
    TB(t, 0, 0, 0);
    TB(t + 1, 32768, 64, 1);
  }
#undef TB

  if constexpr (EPI == 0) {
    ushort_t* P = (ushort_t*)outPtr + (size_t)batch * oBatch;
#pragma unroll
    for (int mi = 0; mi < 8; ++mi) {
      const int row0 = rowBase + wm * 128 + mi * 16 + lk * 4;
#pragma unroll
      for (int ni = 0; ni < 4; ++ni) {
        const int col = colBase + wn * 64 + ni * 16 + lr;
#pragma unroll
        for (int r = 0; r < 4; ++r)
          P[(size_t)(row0 + r) * NP + col] = f2b(acc[mi][ni][r] * scale);
      }
    }
  } else if constexpr (EPI == 1) {
    float* O = (float*)outPtr;
    constexpr int OWN = Ww / PW;
    constexpr int OHW = (Hh / PH) * OWN;
    constexpr int PHPW = PH * PW;
#pragma unroll
    for (int mi = 0; mi < 8; ++mi) {
#pragma unroll
      for (int ni = 0; ni < 4; ++ni) {
        const int d = colBase + wn * 64 + ni * 16 + lr;
        const int c   = d >> ilog2c(PHPW);
        const int pyx = d & (PHPW - 1);
        const int py  = pyx >> ilog2c(PW);
        const int px  = pyx & (PW - 1);
#pragma unroll
        for (int r = 0; r < 4; ++r) {
          const int qq = rowBase + wm * 128 + mi * 16 + lk * 4 + r;
          const int tt = qq >> ilog2c(OHW);
          const int rm = qq & (OHW - 1);
          const int oh = rm >> ilog2c(OWN);
          const int ow = rm & (OWN - 1);
          size_t off = (((size_t)((batch * Tt + tt) * Cc + CBASE + c)) << 12)
                     + ((oh * PH + py) << 6) + ow * PW + px;
          O[off] = acc[mi][ni][r];
        }
      }
    }
  } else {
    const int nb = gz / KSPLIT;
    float* O = (float*)outPtr + ((size_t)ks * nb + batch) * oBatch;
#pragma unroll
    for (int mi = 0; mi < 8; ++mi) {
      const int row0 = rowBase + wm * 128 + mi * 16 + lk * 4;
#pragma unroll
      for (int ni = 0; ni < 4; ++ni) {
        const int col = colBase + wn * 64 + ni * 16 + lr;
#pragma unroll
        for (int r = 0; r < 4; ++r)
          O[(size_t)(row0 + r) * NP + col] = acc[mi][ni][r] * scale;
      }
    }
  }
}

// ---------------- row softmax over bf16 scores, in place ----------------
template<int NP>
__global__ __launch_bounds__(256) void softmax_rows(ushort_t* __restrict__ P) {
  constexpr int PER = NP / 256;
  constexpr int CH  = NP / 1024;
  ushort_t* row = P + (size_t)blockIdx.x * NP;
  const int tid = threadIdx.x;
  float v[PER];
  #pragma unroll
  for (int j = 0; j < CH; ++j) {
    short4v s = *(const short4v*)(row + j * 1024 + tid * 4);
    #pragma unroll
    for (int jj = 0; jj < 4; ++jj) v[4 * j + jj] = b2f((ushort_t)s[jj]);
  }
  float m = -1e30f;
  #pragma unroll
  for (int j = 0; j < PER; ++j) m = fmaxf(m, v[j]);
  #pragma unroll
  for (int o = 32; o >= 1; o >>= 1) m = fmaxf(m, __shfl_xor(m, o));
  __shared__ float redm[4];
  if ((tid & 63) == 0) redm[tid >> 6] = m;
  __syncthreads();
  m = fmaxf(fmaxf(redm[0], redm[1]), fmaxf(redm[2], redm[3]));
  float sum = 0.f;
  #pragma unroll
  for (int j = 0; j < PER; ++j) { v[j] = __expf(v[j] - m); sum += v[j]; }
  #pragma unroll
  for (int o = 32; o >= 1; o >>= 1) sum += __shfl_xor(sum, o);
  __shared__ float reds[4];
  if ((tid & 63) == 0) reds[tid >> 6] = sum;
  __syncthreads();
  sum = reds[0] + reds[1] + reds[2] + reds[3];
  const float inv = 1.0f / sum;
  #pragma unroll
  for (int j = 0; j < CH; ++j) {
    short4v o;
    #pragma unroll
    for (int jj = 0; jj < 4; ++jj) o[jj] = (short)f2b(v[4 * j + jj] * inv);
    *(short4v*)(row + j * 1024 + tid * 4) = o;
  }
}

// ---------------- combine 8 fp32 split-K partials + softmax -> bf16 P (patch 0, NP=1024) ----------------
__global__ __launch_bounds__(256) void softmax_combine_p0(const float* __restrict__ part,
                                                          ushort_t* __restrict__ P) {
  const int tid = threadIdx.x;
  const int b = blockIdx.x >> 10;          // batch
  const int m = blockIdx.x & 1023;         // row within batch
  float v[4] = {0.f, 0.f, 0.f, 0.f};
  #pragma unroll
  for (int ks = 0; ks < 8; ++ks) {
    const float* r = part + ((size_t)(ks * 2 + b) * 1024 + m) * 1024 + tid * 4;
    float4 a = *(const float4*)r;
    v[0] += a.x; v[1] += a.y; v[2] += a.z; v[3] += a.w;
  }
  float mx = fmaxf(fmaxf(v[0], v[1]), fmaxf(v[2], v[3]));
  #pragma unroll
  for (int o = 32; o >= 1; o >>= 1) mx = fmaxf(mx, __shfl_xor(mx, o));
  __shared__ float redm[4], reds[4];
  if ((tid & 63) == 0) redm[tid >> 6] = mx;
  __syncthreads();
  mx = fmaxf(fmaxf(redm[0], redm[1]), fmaxf(redm[2], redm[3]));
  float sum = 0.f;
  #pragma unroll
  for (int j = 0; j < 4; ++j) { v[j] = __expf(v[j] - mx); sum += v[j]; }
  #pragma unroll
  for (int o = 32; o >= 1; o >>= 1) sum += __shfl_xor(sum, o);
  if ((tid & 63) == 0) reds[tid >> 6] = sum;
  __syncthreads();
  sum = reds[0] + reds[1] + reds[2] + reds[3];
  const float inv = 1.0f / sum;
  short4v o4;
  #pragma unroll
  for (int j = 0; j < 4; ++j) o4[j] = (short)f2b(v[j] * inv);
  *(short4v*)(P + ((size_t)(b * 1024 + m)) * 1024 + tid * 4) = o4;
}

extern "C" void kernel_launch(void* const* d_in, const int* in_sizes, int n_in,
                              void* d_out, int out_size, void* d_ws, size_t ws_size,
                              hipStream_t stream) {
  const float* q = (const float*)d_in[0];
  const float* k = (const float*)d_in[1];
  const float* v = (const float*)d_in[2];
  ushort_t* wsA = (ushort_t*)d_ws;
  ushort_t* wsB = wsA + (size_t)33554432;          // 64 MiB in
  ushort_t* wsP = wsB + (size_t)33554432;          // 128 MiB in
  const size_t P1OFF = 16777216;                   // patch-1 offset within A/B regions (elems)
  const size_t PP1   = 2097152;                    // patch-1 offset within P region (elems)
  float* part = (float*)(wsP + PP1);               // QK-p0 split-K partials (64 MiB), overlaid on P-p1 region

  // tokenize Q, K
  tok_qk<8, 8, 0,   1024><<<8192,  256, 0, stream>>>(q, wsA);
  tok_qk<4, 4, 128, 4096><<<16384, 256, 0, stream>>>(q, wsA + P1OFF);
  tok_qk<8, 8, 0,   1024><<<8192,  256, 0, stream>>>(k, wsB);
  tok_qk<4, 4, 128, 4096><<<16384, 256, 0, stream>>>(k, wsB + P1OFF);

  // QK p0: split-K=8 -> fp32 partials [ks][b][1024][1024]; fused combine+softmax
  gemm_pipe<2, 8, 8192, 1024, 1, 1, 0><<<dim3(4, 4, 16), 512, 0, stream>>>(
      wsA, wsB, (size_t)1024 * 8192, (size_t)1024 * 8192, 16,
      part, (size_t)1048576, 0.011048543456039806f);
  softmax_combine_p0<<<2048, 256, 0, stream>>>(part, wsP);

  // QK p1 (overwrites partial region AFTER combine consumed it)
  gemm_pipe<0, 1, 2048, 4096, 1, 1, 0><<<dim3(16, 16, 2), 512, 0, stream>>>(
      wsA + P1OFF, wsB + P1OFF, (size_t)4096 * 2048, (size_t)4096 * 2048, 32,
      wsP + PP1, (size_t)4096 * 4096, 0.022097086912079612f);
  softmax_rows<4096><<<8192, 256, 0, stream>>>(wsP + PP1);

  // tokenize V transposed into A region (Q tokens no longer needed)
  tok_vt<8, 8, 0,   1024><<<8192,  256, 0, stream>>>(v, wsA);
  tok_vt<4, 4, 128, 4096><<<16384, 256, 0, stream>>>(v, wsA + P1OFF);

  // O = P * V -> scatter fp32 into d_out
  gemm_pipe<1, 1, 1024, 0, 8, 8, 0><<<dim3(32, 4, 2), 512, 0, stream>>>(
      wsP, wsA, (size_t)1024 * 1024, (size_t)8192 * 1024, 16, d_out, 0, 1.0f);
  gemm_pipe<1, 1, 4096, 0, 4, 4, 128><<<dim3(8, 16, 2), 512, 0, stream>>>(
      wsP + PP1, wsA + P1OFF, (size_t)4096 * 4096, (size_t)2048 * 4096, 64, d_out, 0, 1.0f);
}

// Round 9
// 500.700 us; speedup vs baseline: 1.7976x; 1.2179x over previous
//
#include <hip/hip_runtime.h>
#include <hip/hip_bf16.h>
#include <stdint.h>

typedef unsigned short ushort_t;
typedef unsigned int uint_t;

typedef __bf16 bf16x8 __attribute__((ext_vector_type(8)));
typedef float f32x4 __attribute__((ext_vector_type(4)));
typedef short short4v __attribute__((ext_vector_type(4)));
typedef short short8v __attribute__((ext_vector_type(8)));

typedef const __attribute__((address_space(1))) void gv_t;
typedef __attribute__((address_space(3))) void lv_t;

__device__ __forceinline__ ushort_t f2b(float f) {
  uint_t u = __builtin_bit_cast(uint_t, f);
  u += 0x7FFFu + ((u >> 16) & 1u);   // round-to-nearest-even
  return (ushort_t)(u >> 16);
}
__device__ __forceinline__ float b2f(ushort_t s) {
  return __builtin_bit_cast(float, (uint_t)s << 16);
}
constexpr int ilog2c(int x) { return x <= 1 ? 0 : 1 + ilog2c(x >> 1); }

constexpr int Tt = 16, Cc = 256, Hh = 64, Ww = 64, DKc = 128;
constexpr size_t P1OFFc = 16777216;   // patch-1 offset within token regions (elems)

// ---------------- tokenize Q/K via LDS tile: (B*T,C,64,64) -> token layouts ----------------
// one block per (b,t,c) image; c<128 -> patch0 (8x8), else patch1 (4x4)
__global__ __launch_bounds__(256) void tok_qk2(const float* __restrict__ src, ushort_t* __restrict__ dst) {
  __shared__ float lds[64][66];
  const int blk = blockIdx.x;
  const int c  = blk & 255;
  const int bt = blk >> 8;
  const int b  = bt >> 4, t = bt & 15;
  const int tid = threadIdx.x;
  const float* img = src + ((size_t)blk << 12);
  {
    const int h = tid >> 2, w0 = (tid & 3) << 4;
    const float* s = img + h * 64 + w0;
#pragma unroll
    for (int j = 0; j < 8; ++j)
      *(float2*)&lds[h][w0 + j * 2] = *(const float2*)(s + j * 2);
  }
  __syncthreads();
  if (c < 128) {
    // n_local = oh*8+ow ; dd = c*64 + py*8+px ; D=8192, N=1024
    const int n  = tid >> 2, q = tid & 3;
    const int oh = n >> 3, ow = n & 7;
    ushort_t* out = dst + (((size_t)(b * 1024 + t * 64 + n)) << 13) + c * 64 + q * 16;
    short8v o0, o1;
#pragma unroll
    for (int j = 0; j < 8; ++j) {
      const int py = q * 2 + (j >> 3), px = j & 7;
      o0[j] = (short)f2b(lds[oh * 8 + py][ow * 8 + px]);
    }
#pragma unroll
    for (int j = 8; j < 16; ++j) {
      const int py = q * 2 + (j >> 3), px = j & 7;
      o1[j - 8] = (short)f2b(lds[oh * 8 + py][ow * 8 + px]);
    }
    *(short8v*)out = o0;
    *(short8v*)(out + 8) = o1;
  } else {
    // n = t*256 + oh*16+ow ; dd = c'*16 + py*4+px ; D=2048, N=4096
    const int n = tid;
    const int oh = n >> 4, ow = n & 15;
    ushort_t* out = dst + P1OFFc + (((size_t)(b * 4096 + t * 256 + n)) << 11) + (c - 128) * 16;
    short8v o0, o1;
#pragma unroll
    for (int j = 0; j < 8; ++j)
      o0[j] = (short)f2b(lds[oh * 4 + (j >> 2)][ow * 4 + (j & 3)]);
#pragma unroll
    for (int j = 8; j < 16; ++j)
      o1[j - 8] = (short)f2b(lds[oh * 4 + (j >> 2)][ow * 4 + (j & 3)]);
    *(short8v*)out = o0;
    *(short8v*)(out + 8) = o1;
  }
}

// ---------------- tokenize V transposed via LDS tile: -> (b, d, n) ----------------
__global__ __launch_bounds__(256) void tok_v2(const float* __restrict__ src, ushort_t* __restrict__ dst) {
  __shared__ float lds[64][66];
  const int blk = blockIdx.x;
  const int c  = blk & 255;
  const int bt = blk >> 8;
  const int b  = bt >> 4, t = bt & 15;
  const int tid = threadIdx.x;
  const float* img = src + ((size_t)blk << 12);
  {
    const int h = tid >> 2, w0 = (tid & 3) << 4;
    const float* s = img + h * 64 + w0;
#pragma unroll
    for (int j = 0; j < 8; ++j)
      *(float2*)&lds[h][w0 + j * 2] = *(const float2*)(s + j * 2);
  }
  __syncthreads();
  if (c < 128) {
    // row dd = c*64 + py*8+px (ld 1024); cols t*64 + n, n = oh*8+ow
    const int dd = tid >> 2, cc = tid & 3;
    const int py = dd >> 3, px = dd & 7;
    ushort_t* out = dst + (((size_t)(b * 8192 + c * 64 + dd)) << 10) + t * 64 + cc * 16;
    short8v o0, o1;
#pragma unroll
    for (int j = 0; j < 8; ++j) {
      const int n = cc * 16 + j;
      o0[j] = (short)f2b(lds[(n >> 3) * 8 + py][(n & 7) * 8 + px]);
    }
#pragma unroll
    for (int j = 8; j < 16; ++j) {
      const int n = cc * 16 + j;
      o1[j - 8] = (short)f2b(lds[(n >> 3) * 8 + py][(n & 7) * 8 + px]);
    }
    *(short8v*)out = o0;
    *(short8v*)(out + 8) = o1;
  } else {
    // row dd = c'*16 + py*4+px (ld 4096); cols t*256 + n, n = oh*16+ow (oh=cc, ow=j)
    const int dd = tid >> 4, cc = tid & 15;
    const int py = dd >> 2, px = dd & 3;
    ushort_t* out = dst + P1OFFc + (((size_t)(b * 2048 + (c - 128) * 16 + dd)) << 12) + t * 256 + cc * 16;
    short8v o0, o1;
#pragma unroll
    for (int j = 0; j < 8; ++j)
      o0[j] = (short)f2b(lds[cc * 4 + py][j * 4 + px]);
#pragma unroll
    for (int j = 8; j < 16; ++j)
      o1[j - 8] = (short)f2b(lds[cc * 4 + py][j * 4 + px]);
    *(short8v*)out = o0;
    *(short8v*)(out + 8) = o1;
  }
}

__device__ __forceinline__ void waitvm8() { asm volatile("s_waitcnt vmcnt(8)" ::: "memory"); }
__device__ __forceinline__ void waitvm6() { asm volatile("s_waitcnt vmcnt(6)" ::: "memory"); }
__device__ __forceinline__ void waitvm0() { asm volatile("s_waitcnt vmcnt(0)" ::: "memory"); }

// ---- 256x256/BK=64 double-buffered NT GEMM, 4 quadrant-phases/K-tile (R8-verified) ----
template<int EPI, int KSPLIT, int LDK, int NP, int PH, int PW, int CBASE>
__global__ __launch_bounds__(512, 2)
void gemm_pipe(const ushort_t* __restrict__ A, const ushort_t* __restrict__ B,
               size_t aBatch, size_t bBatch, int nt,
               void* __restrict__ outPtr, size_t oBatch, float scale) {
  __shared__ __align__(16) ushort_t As[2 * 256 * 64];
  __shared__ __align__(16) ushort_t Bs[2 * 256 * 64];

  const int tid = threadIdx.x;
  const int w = tid >> 6, l = tid & 63;
  const int wm = w >> 2, wn = w & 3;
  const int lr = l & 15, lk = l >> 4;
  const int srow8 = tid >> 3;
  const int gcolS = (((tid & 7) ^ (srow8 & 7)) << 3);
  const int sw0 = ((lk ^ (lr & 7)) << 4);
  const int sw1 = sw0 ^ 64;

  const int gx = gridDim.x, gy = gridDim.y, gz = gridDim.z;
  int id = (blockIdx.z * gy + blockIdx.y) * gx + blockIdx.x;
  const int cpx = (gx * gy * gz) >> 3;
  id = (id & 7) * cpx + (id >> 3);
  const int bx = id % gx;
  const int rst = id / gx;
  const int by = rst % gy;
  const int bz = rst / gy;

  int batch = bz, ks = 0;
  if constexpr (KSPLIT > 1) { batch = bz / KSPLIT; ks = bz - batch * KSPLIT; }

  const int rowBase = by * 256, colBase = bx * 256;
  const ushort_t* Ab = A + (size_t)batch * aBatch + (size_t)ks * nt * 64;
  const ushort_t* Bb = B + (size_t)batch * bBatch + (size_t)ks * nt * 64;

  const ushort_t* pA[4];
  const ushort_t* pB[4];
#pragma unroll
  for (int r = 0; r < 4; ++r) {
    pA[r] = Ab + (size_t)(rowBase + r * 64 + srow8) * LDK + gcolS;
    pB[r] = Bb + (size_t)(colBase + r * 64 + srow8) * LDK + gcolS;
  }

  const char* ArdBase0 = (const char*)As + (wm * 128 + lr) * 128 + sw0;
  const char* ArdBase1 = (const char*)As + (wm * 128 + lr) * 128 + sw1;
  const char* BrdBase0 = (const char*)Bs + (wn * 64 + lr) * 128 + sw0;
  const char* BrdBase1 = (const char*)Bs + (wn * 64 + lr) * 128 + sw1;

  f32x4 acc[8][4] = {};
  bf16x8 Am0[8], Am1[8], Bn0[4], Bn1[4];

  auto stgA = [&](int bufB, int r, int elemOff) {
    __builtin_amdgcn_global_load_lds((gv_t*)(pA[r] + elemOff),
        (lv_t*)((char*)As + bufB + r * 8192 + w * 1024), 16, 0, 0);
  };
  auto stgB = [&](int bufB, int r, int elemOff) {
    __builtin_amdgcn_global_load_lds((gv_t*)(pB[r] + elemOff),
        (lv_t*)((char*)Bs + bufB + r * 8192 + w * 1024), 16, 0, 0);
  };
  auto rdA = [&](int off, bf16x8* dst) {
#pragma unroll
    for (int mi = 0; mi < 4; ++mi) {
      dst[mi * 2 + 0] = *(const bf16x8*)(ArdBase0 + off + mi * 2048);
      dst[mi * 2 + 1] = *(const bf16x8*)(ArdBase1 + off + mi * 2048);
    }
  };
  auto rdB = [&](int off, bf16x8* dst) {
#pragma unroll
    for (int ni = 0; ni < 2; ++ni) {
      dst[ni * 2 + 0] = *(const bf16x8*)(BrdBase0 + off + ni * 2048);
      dst[ni * 2 + 1] = *(const bf16x8*)(BrdBase1 + off + ni * 2048);
    }
  };
  auto mmq = [&](const bf16x8* a, const bf16x8* b, int mh, int nh) {
    __builtin_amdgcn_s_setprio(1);
#pragma unroll
    for (int mi = 0; mi < 4; ++mi)
#pragma unroll
      for (int ni = 0; ni < 2; ++ni) {
        f32x4& cc = acc[mh * 4 + mi][nh * 2 + ni];
        cc = __builtin_amdgcn_mfma_f32_16x16x32_bf16(a[mi * 2 + 0], b[ni * 2 + 0], cc, 0, 0, 0);
        cc = __builtin_amdgcn_mfma_f32_16x16x32_bf16(a[mi * 2 + 1], b[ni * 2 + 1], cc, 0, 0, 0);
      }
    __builtin_amdgcn_s_setprio(0);
  };

#pragma unroll
  for (int r = 0; r < 4; ++r) stgA(0, r, 0);
#pragma unroll
  for (int r = 0; r < 4; ++r) stgB(0, r, 0);
#pragma unroll
  for (int r = 0; r < 4; ++r) stgA(32768, r, 64);
#pragma unroll
  for (int r = 0; r < 4; ++r) stgB(32768, r, 64);
#pragma unroll
  for (int r = 0; r < 4; ++r) { pA[r] += 128; pB[r] += 128; }
  waitvm8();
  __builtin_amdgcn_s_barrier();
  rdA(0, Am0);
  rdB(0, Bn0);

#define TB(T, BUFB, EOFF, ADV) do {                                             \
    const int OB = (BUFB) ^ 32768;                                              \
    rdB((BUFB) + 4096, Bn1);                                                    \
    mmq(Am0, Bn0, 0, 0);                                                        \
    __builtin_amdgcn_s_barrier();                                               \
    rdA((BUFB) + 8192, Am1);                                                    \
    if ((T) + 2 < nt) { stgA((BUFB), 0, (EOFF)); stgA((BUFB), 2, (EOFF)); }     \
    mmq(Am0, Bn1, 0, 1);                                                        \
    __builtin_amdgcn_s_barrier();                                               \
    if ((T) + 2 < nt) { stgB((BUFB), 0, (EOFF)); stgB((BUFB), 1, (EOFF));       \
                        stgB((BUFB), 2, (EOFF)); stgB((BUFB), 3, (EOFF)); }     \
    mmq(Am1, Bn0, 1, 0);                                                        \
    if ((T) + 2 < nt) waitvm6(); else if ((T) + 1 < nt) waitvm0();              \
    __builtin_amdgcn_s_barrier();                                               \
    if ((T) + 1 < nt) { rdA(OB, Am0); rdB(OB, Bn0); }                           \
    if ((T) + 2 < nt) {                                                         \
      stgA((BUFB), 1, (EOFF)); stgA((BUFB), 3, (EOFF));                         \
      if (ADV) {                                                                \
        _Pragma("unroll")                                                       \
        for (int r = 0; r < 4; ++r) { pA[r] += 128; pB[r] += 128; }             \
      }                                                                         \
    }                                                                           \
    mmq(Am1, Bn1, 1, 1);                                                        \
    __builtin_amdgcn_s_barrier();                                               \
  } while (0)

  for (int t = 0; t < nt; t += 2) {
    TB(t, 0, 0, 0);
    TB(t + 1, 32768, 64, 1);
  }
#undef TB

  if constexpr (EPI == 0) {
    ushort_t* P = (ushort_t*)outPtr + (size_t)batch * oBatch;
#pragma unroll
    for (int mi = 0; mi < 8; ++mi) {
      const int row0 = rowBase + wm * 128 + mi * 16 + lk * 4;
#pragma unroll
      for (int ni = 0; ni < 4; ++ni) {
        const int col = colBase + wn * 64 + ni * 16 + lr;
#pragma unroll
        for (int r = 0; r < 4; ++r)
          P[(size_t)(row0 + r) * NP + col] = f2b(acc[mi][ni][r] * scale);
      }
    }
  } else if constexpr (EPI == 1) {
    float* O = (float*)outPtr;
    constexpr int OWN = Ww / PW;
    constexpr int OHW = (Hh / PH) * OWN;
    constexpr int PHPW = PH * PW;
#pragma unroll
    for (int mi = 0; mi < 8; ++mi) {
#pragma unroll
      for (int ni = 0; ni < 4; ++ni) {
        const int d = colBase + wn * 64 + ni * 16 + lr;
        const int c   = d >> ilog2c(PHPW);
        const int pyx = d & (PHPW - 1);
        const int py  = pyx >> ilog2c(PW);
        const int px  = pyx & (PW - 1);
#pragma unroll
        for (int r = 0; r < 4; ++r) {
          const int qq = rowBase + wm * 128 + mi * 16 + lk * 4 + r;
          const int tt = qq >> ilog2c(OHW);
          const int rm = qq & (OHW - 1);
          const int oh = rm >> ilog2c(OWN);
          const int ow = rm & (OWN - 1);
          size_t off = (((size_t)((batch * Tt + tt) * Cc + CBASE + c)) << 12)
                     + ((oh * PH + py) << 6) + ow * PW + px;
          O[off] = acc[mi][ni][r];
        }
      }
    }
  } else {
    const int nb = gz / KSPLIT;
    float* O = (float*)outPtr + ((size_t)ks * nb + batch) * oBatch;
#pragma unroll
    for (int mi = 0; mi < 8; ++mi) {
      const int row0 = rowBase + wm * 128 + mi * 16 + lk * 4;
#pragma unroll
      for (int ni = 0; ni < 4; ++ni) {
        const int col = colBase + wn * 64 + ni * 16 + lr;
#pragma unroll
        for (int r = 0; r < 4; ++r)
          O[(size_t)(row0 + r) * NP + col] = acc[mi][ni][r] * scale;
      }
    }
  }
}

// ---------------- row softmax over bf16 scores, in place ----------------
template<int NP>
__global__ __launch_bounds__(256) void softmax_rows(ushort_t* __restrict__ P) {
  constexpr int PER = NP / 256;
  constexpr int CH  = NP / 1024;
  ushort_t* row = P + (size_t)blockIdx.x * NP;
  const int tid = threadIdx.x;
  float v[PER];
  #pragma unroll
  for (int j = 0; j < CH; ++j) {
    short4v s = *(const short4v*)(row + j * 1024 + tid * 4);
    #pragma unroll
    for (int jj = 0; jj < 4; ++jj) v[4 * j + jj] = b2f((ushort_t)s[jj]);
  }
  float m = -1e30f;
  #pragma unroll
  for (int j = 0; j < PER; ++j) m = fmaxf(m, v[j]);
  #pragma unroll
  for (int o = 32; o >= 1; o >>= 1) m = fmaxf(m, __shfl_xor(m, o));
  __shared__ float redm[4];
  if ((tid & 63) == 0) redm[tid >> 6] = m;
  __syncthreads();
  m = fmaxf(fmaxf(redm[0], redm[1]), fmaxf(redm[2], redm[3]));
  float sum = 0.f;
  #pragma unroll
  for (int j = 0; j < PER; ++j) { v[j] = __expf(v[j] - m); sum += v[j]; }
  #pragma unroll
  for (int o = 32; o >= 1; o >>= 1) sum += __shfl_xor(sum, o);
  __shared__ float reds[4];
  if ((tid & 63) == 0) reds[tid >> 6] = sum;
  __syncthreads();
  sum = reds[0] + reds[1] + reds[2] + reds[3];
  const float inv = 1.0f / sum;
  #pragma unroll
  for (int j = 0; j < CH; ++j) {
    short4v o;
    #pragma unroll
    for (int jj = 0; jj < 4; ++jj) o[jj] = (short)f2b(v[4 * j + jj] * inv);
    *(short4v*)(row + j * 1024 + tid * 4) = o;
  }
}

// ---------------- combine 8 fp32 split-K partials + softmax -> bf16 P (patch 0) ----------------
__global__ __launch_bounds__(256) void softmax_combine_p0(const float* __restrict__ part,
                                                          ushort_t* __restrict__ P) {
  const int tid = threadIdx.x;
  const int b = blockIdx.x >> 10;
  const int m = blockIdx.x & 1023;
  float v[4] = {0.f, 0.f, 0.f, 0.f};
  #pragma unroll
  for (int ks = 0; ks < 8; ++ks) {
    const float* r = part + ((size_t)(ks * 2 + b) * 1024 + m) * 1024 + tid * 4;
    float4 a = *(const float4*)r;
    v[0] += a.x; v[1] += a.y; v[2] += a.z; v[3] += a.w;
  }
  float mx = fmaxf(fmaxf(v[0], v[1]), fmaxf(v[2], v[3]));
  #pragma unroll
  for (int o = 32; o >= 1; o >>= 1) mx = fmaxf(mx, __shfl_xor(mx, o));
  __shared__ float redm[4], reds[4];
  if ((tid & 63) == 0) redm[tid >> 6] = mx;
  __syncthreads();
  mx = fmaxf(fmaxf(redm[0], redm[1]), fmaxf(redm[2], redm[3]));
  float sum = 0.f;
  #pragma unroll
  for (int j = 0; j < 4; ++j) { v[j] = __expf(v[j] - mx); sum += v[j]; }
  #pragma unroll
  for (int o = 32; o >= 1; o >>= 1) sum += __shfl_xor(sum, o);
  if ((tid & 63) == 0) reds[tid >> 6] = sum;
  __syncthreads();
  sum = reds[0] + reds[1] + reds[2] + reds[3];
  const float inv = 1.0f / sum;
  short4v o4;
  #pragma unroll
  for (int j = 0; j < 4; ++j) o4[j] = (short)f2b(v[j] * inv);
  *(short4v*)(P + ((size_t)(b * 1024 + m)) * 1024 + tid * 4) = o4;
}

extern "C" void kernel_launch(void* const* d_in, const int* in_sizes, int n_in,
                              void* d_out, int out_size, void* d_ws, size_t ws_size,
                              hipStream_t stream) {
  const float* q = (const float*)d_in[0];
  const float* k = (const float*)d_in[1];
  const float* v = (const float*)d_in[2];
  ushort_t* wsA = (ushort_t*)d_ws;
  ushort_t* wsB = wsA + (size_t)33554432;          // 64 MiB in
  ushort_t* wsP = wsB + (size_t)33554432;          // 128 MiB in
  const size_t P1OFF = P1OFFc;                     // patch-1 offset within A/B regions (elems)
  const size_t PP1   = 2097152;                    // patch-1 offset within P region (elems)
  float* part = (float*)(wsP + PP1);               // QK-p0 split-K partials (64 MiB), overlaid on P-p1 region

  // tokenize Q, K (both patches, LDS-tiled)
  tok_qk2<<<8192, 256, 0, stream>>>(q, wsA);
  tok_qk2<<<8192, 256, 0, stream>>>(k, wsB);

  // QK p0: split-K=8 -> fp32 partials [ks][b][1024][1024]; fused combine+softmax
  gemm_pipe<2, 8, 8192, 1024, 1, 1, 0><<<dim3(4, 4, 16), 512, 0, stream>>>(
      wsA, wsB, (size_t)1024 * 8192, (size_t)1024 * 8192, 16,
      part, (size_t)1048576, 0.011048543456039806f);
  softmax_combine_p0<<<2048, 256, 0, stream>>>(part, wsP);

  // QK p1 (overwrites partial region AFTER combine consumed it)
  gemm_pipe<0, 1, 2048, 4096, 1, 1, 0><<<dim3(16, 16, 2), 512, 0, stream>>>(
      wsA + P1OFF, wsB + P1OFF, (size_t)4096 * 2048, (size_t)4096 * 2048, 32,
      wsP + PP1, (size_t)4096 * 4096, 0.022097086912079612f);
  softmax_rows<4096><<<8192, 256, 0, stream>>>(wsP + PP1);

  // tokenize V transposed into A region (Q tokens no longer needed)
  tok_v2<<<8192, 256, 0, stream>>>(v, wsA);

  // O = P * V -> scatter fp32 into d_out
  gemm_pipe<1, 1, 1024, 0, 8, 8, 0><<<dim3(32, 4, 2), 512, 0, stream>>>(
      wsP, wsA, (size_t)1024 * 1024, (size_t)8192 * 1024, 16, d_out, 0, 1.0f);
  gemm_pipe<1, 1, 4096, 0, 4, 4, 128><<<dim3(8, 16, 2), 512, 0, stream>>>(
      wsP + PP1, wsA + P1OFF, (size_t)4096 * 4096, (size_t)2048 * 4096, 64, d_out, 0, 1.0f);
}

// Round 10
// 489.271 us; speedup vs baseline: 1.8396x; 1.0234x over previous
//
#include <hip/hip_runtime.h>
#include <hip/hip_bf16.h>
#include <stdint.h>

typedef unsigned short ushort_t;
typedef unsigned int uint_t;

typedef __bf16 bf16x8 __attribute__((ext_vector_type(8)));
typedef float f32x4 __attribute__((ext_vector_type(4)));
typedef short short4v __attribute__((ext_vector_type(4)));
typedef short short8v __attribute__((ext_vector_type(8)));

typedef const __attribute__((address_space(1))) void gv_t;
typedef __attribute__((address_space(3))) void lv_t;

__device__ __forceinline__ ushort_t f2b(float f) {
  uint_t u = __builtin_bit_cast(uint_t, f);
  u += 0x7FFFu + ((u >> 16) & 1u);   // round-to-nearest-even
  return (ushort_t)(u >> 16);
}
__device__ __forceinline__ float b2f(ushort_t s) {
  return __builtin_bit_cast(float, (uint_t)s << 16);
}
constexpr int ilog2c(int x) { return x <= 1 ? 0 : 1 + ilog2c(x >> 1); }

constexpr int Tt = 16, Cc = 256, Hh = 64, Ww = 64, DKc = 128;
constexpr size_t P1OFFc = 16777216;   // patch-1 offset within token regions (elems)

// ---------------- tokenize Q and K via LDS tile (merged): (B*T,C,64,64) -> token layouts ----------------
// grid 16384: blk>>13 selects {Q,K}; one block per (b,t,c) image; c<128 -> patch0, else patch1
__global__ __launch_bounds__(256) void tok_qk2(const float* __restrict__ srcQ, const float* __restrict__ srcK,
                                               ushort_t* __restrict__ dstQ, ushort_t* __restrict__ dstK) {
  __shared__ float lds[64][66];
  const int sel = blockIdx.x >> 13;
  const int blk = blockIdx.x & 8191;
  const float* src = sel ? srcK : srcQ;
  ushort_t* dst = sel ? dstK : dstQ;
  const int c  = blk & 255;
  const int bt = blk >> 8;
  const int b  = bt >> 4, t = bt & 15;
  const int tid = threadIdx.x;
  const float* img = src + ((size_t)blk << 12);
  {
    const int h = tid >> 2, w0 = (tid & 3) << 4;
    const float* s = img + h * 64 + w0;
#pragma unroll
    for (int j = 0; j < 8; ++j)
      *(float2*)&lds[h][w0 + j * 2] = *(const float2*)(s + j * 2);
  }
  __syncthreads();
  if (c < 128) {
    const int n  = tid >> 2, q = tid & 3;
    const int oh = n >> 3, ow = n & 7;
    ushort_t* out = dst + (((size_t)(b * 1024 + t * 64 + n)) << 13) + c * 64 + q * 16;
    short8v o0, o1;
#pragma unroll
    for (int j = 0; j < 8; ++j) {
      const int py = q * 2 + (j >> 3), px = j & 7;
      o0[j] = (short)f2b(lds[oh * 8 + py][ow * 8 + px]);
    }
#pragma unroll
    for (int j = 8; j < 16; ++j) {
      const int py = q * 2 + (j >> 3), px = j & 7;
      o1[j - 8] = (short)f2b(lds[oh * 8 + py][ow * 8 + px]);
    }
    *(short8v*)out = o0;
    *(short8v*)(out + 8) = o1;
  } else {
    const int n = tid;
    const int oh = n >> 4, ow = n & 15;
    ushort_t* out = dst + P1OFFc + (((size_t)(b * 4096 + t * 256 + n)) << 11) + (c - 128) * 16;
    short8v o0, o1;
#pragma unroll
    for (int j = 0; j < 8; ++j)
      o0[j] = (short)f2b(lds[oh * 4 + (j >> 2)][ow * 4 + (j & 3)]);
#pragma unroll
    for (int j = 8; j < 16; ++j)
      o1[j - 8] = (short)f2b(lds[oh * 4 + (j >> 2)][ow * 4 + (j & 3)]);
    *(short8v*)out = o0;
    *(short8v*)(out + 8) = o1;
  }
}

// ---------------- tokenize V transposed via LDS tile: -> (b, d, n) ----------------
__global__ __launch_bounds__(256) void tok_v2(const float* __restrict__ src, ushort_t* __restrict__ dst) {
  __shared__ float lds[64][66];
  const int blk = blockIdx.x;
  const int c  = blk & 255;
  const int bt = blk >> 8;
  const int b  = bt >> 4, t = bt & 15;
  const int tid = threadIdx.x;
  const float* img = src + ((size_t)blk << 12);
  {
    const int h = tid >> 2, w0 = (tid & 3) << 4;
    const float* s = img + h * 64 + w0;
#pragma unroll
    for (int j = 0; j < 8; ++j)
      *(float2*)&lds[h][w0 + j * 2] = *(const float2*)(s + j * 2);
  }
  __syncthreads();
  if (c < 128) {
    const int dd = tid >> 2, cc = tid & 3;
    const int py = dd >> 3, px = dd & 7;
    ushort_t* out = dst + (((size_t)(b * 8192 + c * 64 + dd)) << 10) + t * 64 + cc * 16;
    short8v o0, o1;
#pragma unroll
    for (int j = 0; j < 8; ++j) {
      const int n = cc * 16 + j;
      o0[j] = (short)f2b(lds[(n >> 3) * 8 + py][(n & 7) * 8 + px]);
    }
#pragma unroll
    for (int j = 8; j < 16; ++j) {
      const int n = cc * 16 + j;
      o1[j - 8] = (short)f2b(lds[(n >> 3) * 8 + py][(n & 7) * 8 + px]);
    }
    *(short8v*)out = o0;
    *(short8v*)(out + 8) = o1;
  } else {
    const int dd = tid >> 4, cc = tid & 15;
    const int py = dd >> 2, px = dd & 3;
    ushort_t* out = dst + P1OFFc + (((size_t)(b * 2048 + (c - 128) * 16 + dd)) << 12) + t * 256 + cc * 16;
    short8v o0, o1;
#pragma unroll
    for (int j = 0; j < 8; ++j)
      o0[j] = (short)f2b(lds[cc * 4 + py][j * 4 + px]);
#pragma unroll
    for (int j = 8; j < 16; ++j)
      o1[j - 8] = (short)f2b(lds[cc * 4 + py][j * 4 + px]);
    *(short8v*)out = o0;
    *(short8v*)(out + 8) = o1;
  }
}

__device__ __forceinline__ void waitvm8() { asm volatile("s_waitcnt vmcnt(8)" ::: "memory"); }
__device__ __forceinline__ void waitvm6() { asm volatile("s_waitcnt vmcnt(6)" ::: "memory"); }
__device__ __forceinline__ void waitvm0() { asm volatile("s_waitcnt vmcnt(0)" ::: "memory"); }

// ---- 256x256/BK=64 double-buffered NT GEMM, 4 quadrant-phases/K-tile (R8-verified) ----
// EPI 0: bf16 scores*scale -> P ; EPI 1: fp32 from_tokens scatter ; EPI 2: bf16 split-K partial
template<int EPI, int KSPLIT, int LDK, int NP, int PH, int PW, int CBASE>
__global__ __launch_bounds__(512, 2)
void gemm_pipe(const ushort_t* __restrict__ A, const ushort_t* __restrict__ B,
               size_t aBatch, size_t bBatch, int nt,
               void* __restrict__ outPtr, size_t oBatch, float scale) {
  __shared__ __align__(16) ushort_t As[2 * 256 * 64];
  __shared__ __align__(16) ushort_t Bs[2 * 256 * 64];

  const int tid = threadIdx.x;
  const int w = tid >> 6, l = tid & 63;
  const int wm = w >> 2, wn = w & 3;
  const int lr = l & 15, lk = l >> 4;
  const int srow8 = tid >> 3;
  const int gcolS = (((tid & 7) ^ (srow8 & 7)) << 3);
  const int sw0 = ((lk ^ (lr & 7)) << 4);
  const int sw1 = sw0 ^ 64;

  const int gx = gridDim.x, gy = gridDim.y, gz = gridDim.z;
  int id = (blockIdx.z * gy + blockIdx.y) * gx + blockIdx.x;
  const int cpx = (gx * gy * gz) >> 3;
  id = (id & 7) * cpx + (id >> 3);
  const int bx = id % gx;
  const int rst = id / gx;
  const int by = rst % gy;
  const int bz = rst / gy;

  int batch = bz, ks = 0;
  if constexpr (KSPLIT > 1) { batch = bz / KSPLIT; ks = bz - batch * KSPLIT; }

  const int rowBase = by * 256, colBase = bx * 256;
  const ushort_t* Ab = A + (size_t)batch * aBatch + (size_t)ks * nt * 64;
  const ushort_t* Bb = B + (size_t)batch * bBatch + (size_t)ks * nt * 64;

  const ushort_t* pA[4];
  const ushort_t* pB[4];
#pragma unroll
  for (int r = 0; r < 4; ++r) {
    pA[r] = Ab + (size_t)(rowBase + r * 64 + srow8) * LDK + gcolS;
    pB[r] = Bb + (size_t)(colBase + r * 64 + srow8) * LDK + gcolS;
  }

  const char* ArdBase0 = (const char*)As + (wm * 128 + lr) * 128 + sw0;
  const char* ArdBase1 = (const char*)As + (wm * 128 + lr) * 128 + sw1;
  const char* BrdBase0 = (const char*)Bs + (wn * 64 + lr) * 128 + sw0;
  const char* BrdBase1 = (const char*)Bs + (wn * 64 + lr) * 128 + sw1;

  f32x4 acc[8][4] = {};
  bf16x8 Am0[8], Am1[8], Bn0[4], Bn1[4];

  auto stgA = [&](int bufB, int r, int elemOff) {
    __builtin_amdgcn_global_load_lds((gv_t*)(pA[r] + elemOff),
        (lv_t*)((char*)As + bufB + r * 8192 + w * 1024), 16, 0, 0);
  };
  auto stgB = [&](int bufB, int r, int elemOff) {
    __builtin_amdgcn_global_load_lds((gv_t*)(pB[r] + elemOff),
        (lv_t*)((char*)Bs + bufB + r * 8192 + w * 1024), 16, 0, 0);
  };
  auto rdA = [&](int off, bf16x8* dst) {
#pragma unroll
    for (int mi = 0; mi < 4; ++mi) {
      dst[mi * 2 + 0] = *(const bf16x8*)(ArdBase0 + off + mi * 2048);
      dst[mi * 2 + 1] = *(const bf16x8*)(ArdBase1 + off + mi * 2048);
    }
  };
  auto rdB = [&](int off, bf16x8* dst) {
#pragma unroll
    for (int ni = 0; ni < 2; ++ni) {
      dst[ni * 2 + 0] = *(const bf16x8*)(BrdBase0 + off + ni * 2048);
      dst[ni * 2 + 1] = *(const bf16x8*)(BrdBase1 + off + ni * 2048);
    }
  };
  auto mmq = [&](const bf16x8* a, const bf16x8* b, int mh, int nh) {
    __builtin_amdgcn_s_setprio(1);
#pragma unroll
    for (int mi = 0; mi < 4; ++mi)
#pragma unroll
      for (int ni = 0; ni < 2; ++ni) {
        f32x4& cc = acc[mh * 4 + mi][nh * 2 + ni];
        cc = __builtin_amdgcn_mfma_f32_16x16x32_bf16(a[mi * 2 + 0], b[ni * 2 + 0], cc, 0, 0, 0);
        cc = __builtin_amdgcn_mfma_f32_16x16x32_bf16(a[mi * 2 + 1], b[ni * 2 + 1], cc, 0, 0, 0);
      }
    __builtin_amdgcn_s_setprio(0);
  };

#pragma unroll
  for (int r = 0; r < 4; ++r) stgA(0, r, 0);
#pragma unroll
  for (int r = 0; r < 4; ++r) stgB(0, r, 0);
#pragma unroll
  for (int r = 0; r < 4; ++r) stgA(32768, r, 64);
#pragma unroll
  for (int r = 0; r < 4; ++r) stgB(32768, r, 64);
#pragma unroll
  for (int r = 0; r < 4; ++r) { pA[r] += 128; pB[r] += 128; }
  waitvm8();
  __builtin_amdgcn_s_barrier();
  rdA(0, Am0);
  rdB(0, Bn0);

#define TB(T, BUFB, EOFF, ADV) do {                                             \
    const int OB = (BUFB) ^ 32768;                                              \
    rdB((BUFB) + 4096, Bn1);                                                    \
    mmq(Am0, Bn0, 0, 0);                                                        \
    __builtin_amdgcn_s_barrier();                                               \
    rdA((BUFB) + 8192, Am1);                                                    \
    if ((T) + 2 < nt) { stgA((BUFB), 0, (EOFF)); stgA((BUFB), 2, (EOFF)); }     \
    mmq(Am0, Bn1, 0, 1);                                                        \
    __builtin_amdgcn_s_barrier();                                               \
    if ((T) + 2 < nt) { stgB((BUFB), 0, (EOFF)); stgB((BUFB), 1, (EOFF));       \
                        stgB((BUFB), 2, (EOFF)); stgB((BUFB), 3, (EOFF)); }     \
    mmq(Am1, Bn0, 1, 0);                                                        \
    if ((T) + 2 < nt) waitvm6(); else if ((T) + 1 < nt) waitvm0();              \
    __builtin_amdgcn_s_barrier();                                               \
    if ((T) + 1 < nt) { rdA(OB, Am0); rdB(OB, Bn0); }                           \
    if ((T) + 2 < nt) {                                                         \
      stgA((BUFB), 1, (EOFF)); stgA((BUFB), 3, (EOFF));                         \
      if (ADV) {                                                                \
        _Pragma("unroll")                                                       \
        for (int r = 0; r < 4; ++r) { pA[r] += 128; pB[r] += 128; }             \
      }                                                                         \
    }                                                                           \
    mmq(Am1, Bn1, 1, 1);                                                        \
    __builtin_amdgcn_s_barrier();                                               \
  } while (0)

  for (int t = 0; t < nt; t += 2) {
    TB(t, 0, 0, 0);
    TB(t + 1, 32768, 64, 1);
  }
#undef TB

  if constexpr (EPI == 0) {
    ushort_t* P = (ushort_t*)outPtr + (size_t)batch * oBatch;
#pragma unroll
    for (int mi = 0; mi < 8; ++mi) {
      const int row0 = rowBase + wm * 128 + mi * 16 + lk * 4;
#pragma unroll
      for (int ni = 0; ni < 4; ++ni) {
        const int col = colBase + wn * 64 + ni * 16 + lr;
#pragma unroll
        for (int r = 0; r < 4; ++r)
          P[(size_t)(row0 + r) * NP + col] = f2b(acc[mi][ni][r] * scale);
      }
    }
  } else if constexpr (EPI == 1) {
    float* O = (float*)outPtr;
    constexpr int OWN = Ww / PW;
    constexpr int OHW = (Hh / PH) * OWN;
    constexpr int PHPW = PH * PW;
#pragma unroll
    for (int mi = 0; mi < 8; ++mi) {
#pragma unroll
      for (int ni = 0; ni < 4; ++ni) {
        const int d = colBase + wn * 64 + ni * 16 + lr;
        const int c   = d >> ilog2c(PHPW);
        const int pyx = d & (PHPW - 1);
        const int py  = pyx >> ilog2c(PW);
        const int px  = pyx & (PW - 1);
#pragma unroll
        for (int r = 0; r < 4; ++r) {
          const int qq = rowBase + wm * 128 + mi * 16 + lk * 4 + r;
          const int tt = qq >> ilog2c(OHW);
          const int rm = qq & (OHW - 1);
          const int oh = rm >> ilog2c(OWN);
          const int ow = rm & (OWN - 1);
          size_t off = (((size_t)((batch * Tt + tt) * Cc + CBASE + c)) << 12)
                     + ((oh * PH + py) << 6) + ow * PW + px;
          O[off] = acc[mi][ni][r];
        }
      }
    }
  } else {
    const int nb = gz / KSPLIT;
    ushort_t* O = (ushort_t*)outPtr + ((size_t)ks * nb + batch) * oBatch;
#pragma unroll
    for (int mi = 0; mi < 8; ++mi) {
      const int row0 = rowBase + wm * 128 + mi * 16 + lk * 4;
#pragma unroll
      for (int ni = 0; ni < 4; ++ni) {
        const int col = colBase + wn * 64 + ni * 16 + lr;
#pragma unroll
        for (int r = 0; r < 4; ++r)
          O[(size_t)(row0 + r) * NP + col] = f2b(acc[mi][ni][r] * scale);
      }
    }
  }
}

// ---------------- row softmax over bf16 scores, in place ----------------
template<int NP>
__global__ __launch_bounds__(256) void softmax_rows(ushort_t* __restrict__ P) {
  constexpr int PER = NP / 256;
  constexpr int CH  = NP / 1024;
  ushort_t* row = P + (size_t)blockIdx.x * NP;
  const int tid = threadIdx.x;
  float v[PER];
  #pragma unroll
  for (int j = 0; j < CH; ++j) {
    short4v s = *(const short4v*)(row + j * 1024 + tid * 4);
    #pragma unroll
    for (int jj = 0; jj < 4; ++jj) v[4 * j + jj] = b2f((ushort_t)s[jj]);
  }
  float m = -1e30f;
  #pragma unroll
  for (int j = 0; j < PER; ++j) m = fmaxf(m, v[j]);
  #pragma unroll
  for (int o = 32; o >= 1; o >>= 1) m = fmaxf(m, __shfl_xor(m, o));
  __shared__ float redm[4];
  if ((tid & 63) == 0) redm[tid >> 6] = m;
  __syncthreads();
  m = fmaxf(fmaxf(redm[0], redm[1]), fmaxf(redm[2], redm[3]));
  float sum = 0.f;
  #pragma unroll
  for (int j = 0; j < PER; ++j) { v[j] = __expf(v[j] - m); sum += v[j]; }
  #pragma unroll
  for (int o = 32; o >= 1; o >>= 1) sum += __shfl_xor(sum, o);
  __shared__ float reds[4];
  if ((tid & 63) == 0) reds[tid >> 6] = sum;
  __syncthreads();
  sum = reds[0] + reds[1] + reds[2] + reds[3];
  const float inv = 1.0f / sum;
  #pragma unroll
  for (int j = 0; j < CH; ++j) {
    short4v o;
    #pragma unroll
    for (int jj = 0; jj < 4; ++jj) o[jj] = (short)f2b(v[4 * j + jj] * inv);
    *(short4v*)(row + j * 1024 + tid * 4) = o;
  }
}

// ---------------- combine 8 bf16 split-K partials + softmax -> bf16 P (patch 0) ----------------
__global__ __launch_bounds__(256) void softmax_combine_p0(const ushort_t* __restrict__ part,
                                                          ushort_t* __restrict__ P) {
  const int tid = threadIdx.x;
  const int b = blockIdx.x >> 10;
  const int m = blockIdx.x & 1023;
  float v[4] = {0.f, 0.f, 0.f, 0.f};
  #pragma unroll
  for (int ks = 0; ks < 8; ++ks) {
    short4v a = *(const short4v*)(part + ((size_t)(ks * 2 + b) * 1024 + m) * 1024 + tid * 4);
    #pragma unroll
    for (int j = 0; j < 4; ++j) v[j] += b2f((ushort_t)a[j]);
  }
  float mx = fmaxf(fmaxf(v[0], v[1]), fmaxf(v[2], v[3]));
  #pragma unroll
  for (int o = 32; o >= 1; o >>= 1) mx = fmaxf(mx, __shfl_xor(mx, o));
  __shared__ float redm[4], reds[4];
  if ((tid & 63) == 0) redm[tid >> 6] = mx;
  __syncthreads();
  mx = fmaxf(fmaxf(redm[0], redm[1]), fmaxf(redm[2], redm[3]));
  float sum = 0.f;
  #pragma unroll
  for (int j = 0; j < 4; ++j) { v[j] = __expf(v[j] - mx); sum += v[j]; }
  #pragma unroll
  for (int o = 32; o >= 1; o >>= 1) sum += __shfl_xor(sum, o);
  if ((tid & 63) == 0) reds[tid >> 6] = sum;
  __syncthreads();
  sum = reds[0] + reds[1] + reds[2] + reds[3];
  const float inv = 1.0f / sum;
  short4v o4;
  #pragma unroll
  for (int j = 0; j < 4; ++j) o4[j] = (short)f2b(v[j] * inv);
  *(short4v*)(P + ((size_t)(b * 1024 + m)) * 1024 + tid * 4) = o4;
}

extern "C" void kernel_launch(void* const* d_in, const int* in_sizes, int n_in,
                              void* d_out, int out_size, void* d_ws, size_t ws_size,
                              hipStream_t stream) {
  const float* q = (const float*)d_in[0];
  const float* k = (const float*)d_in[1];
  const float* v = (const float*)d_in[2];
  ushort_t* wsA = (ushort_t*)d_ws;
  ushort_t* wsB = wsA + (size_t)33554432;          // 64 MiB in
  ushort_t* wsP = wsB + (size_t)33554432;          // 128 MiB in
  const size_t P1OFF = P1OFFc;                     // patch-1 offset within A/B regions (elems)
  const size_t PP1   = 2097152;                    // patch-1 offset within P region (elems)
  ushort_t* part = wsP + PP1;                      // QK-p0 bf16 split-K partials (32 MiB), overlaid on P-p1

  // tokenize Q and K (merged, both patches, LDS-tiled)
  tok_qk2<<<16384, 256, 0, stream>>>(q, k, wsA, wsB);

  // QK p0: split-K=8 -> bf16 partials [ks][b][1024][1024]; fused combine+softmax
  gemm_pipe<2, 8, 8192, 1024, 1, 1, 0><<<dim3(4, 4, 16), 512, 0, stream>>>(
      wsA, wsB, (size_t)1024 * 8192, (size_t)1024 * 8192, 16,
      part, (size_t)1048576, 0.011048543456039806f);
  softmax_combine_p0<<<2048, 256, 0, stream>>>(part, wsP);

  // QK p1 (overwrites partial region AFTER combine consumed it)
  gemm_pipe<0, 1, 2048, 4096, 1, 1, 0><<<dim3(16, 16, 2), 512, 0, stream>>>(
      wsA + P1OFF, wsB + P1OFF, (size_t)4096 * 2048, (size_t)4096 * 2048, 32,
      wsP + PP1, (size_t)4096 * 4096, 0.022097086912079612f);
  softmax_rows<4096><<<8192, 256, 0, stream>>>(wsP + PP1);

  // tokenize V transposed into A region (Q tokens no longer needed)
  tok_v2<<<8192, 256, 0, stream>>>(v, wsA);

  // O = P * V -> scatter fp32 into d_out
  gemm_pipe<1, 1, 1024, 0, 8, 8, 0><<<dim3(32, 4, 2), 512, 0, stream>>>(
      wsP, wsA, (size_t)1024 * 1024, (size_t)8192 * 1024, 16, d_out, 0, 1.0f);
  gemm_pipe<1, 1, 4096, 0, 4, 4, 128><<<dim3(8, 16, 2), 512, 0, stream>>>(
      wsP + PP1, wsA + P1OFF, (size_t)4096 * 4096, (size_t)2048 * 4096, 64, d_out, 0, 1.0f);
}